// Round 5
// baseline (631.652 us; speedup 1.0000x reference)
//
#include <hip/hip_runtime.h>
#include <math.h>

#define Dd 128
#define Tt 1024
#define Kk 2048
#define Nn 65536
#define DT 131072  // Dd*Tt

typedef __attribute__((ext_vector_type(8))) short short8;
typedef __attribute__((ext_vector_type(4))) float float4v;

// ws layout (bytes):
//   cbh     @ 0        : ushort[262144] = 524288   (bf16 hi plane of codebook, SOA-fragment layout)
//   e2f     @ 524288   : float[2048]    = 8192     (np-replica fp32 ||e||^2)
//   Arow    @ 532480   : float[65536]   = 262144   (np-replica fp32 ||x||^2)
//   idxbuf  @ 794624   : int[65536]     = 262144
//   counts  @ 1056768  : int[2048]      = 8192
//   part    @ 1064960  : double[512]    = 4096
//   cand_g  @ 1069056  : ushort[65536*16] = 2097152
//   candcnt @ 3166208  : int[65536]     = 262144
// total 3428352 B (~3.43 MB)
//
// cbh SOA layout: for code k, 16B granule g (g of the 256B row):
//   chunk=k>>6, wv=(k>>4)&3, col=k&15, ks=g>>2, quad=g&3
//   byte dest = chunk*16384 + wv*4096 + ks*1024 + quad*256 + col*16
// => score_kernel per-(ct,ks) B-fragment load is lane*16B contiguous (1 KB).

// Fused setup: SOA bf16-hi split of codebook (blocks 0..127), np-replica fp32
// ||e||^2 + counts-zero + part[0..255]-zero (blocks 128..135), np-replica
// fp32 ||x||^2 (blocks 136..391). numpy pairwise order for n=128: 8
// accumulators, sequential i, combine ((r0+r1)+(r2+r3))+((r4+r5)+(r6+r7));
// __f*_rn blocks FMA contraction so each square rounds like numpy.
__global__ __launch_bounds__(256)
void setup_kernel(const float* __restrict__ cb, const float* __restrict__ z,
                  ushort* __restrict__ cbh, float* __restrict__ e2f,
                  float* __restrict__ Arow, int* __restrict__ counts,
                  double* __restrict__ part) {
  const int bid = blockIdx.x, tid = threadIdx.x;
  if (bid < 128) {
    const int gi = bid * 256 + tid;               // 32768 granules (16B each)
    const int k = gi >> 4, g = gi & 15;
    const float* p = cb + (size_t)k * Dd + g * 8; // 32B coalesced read
    short8 w;
    #pragma unroll
    for (int j = 0; j < 8; ++j) {
      const unsigned u = __float_as_uint(p[j]);
      const unsigned hb = (u + 0x7FFFu + ((u >> 16) & 1u)) & 0xFFFF0000u;  // RNE bf16
      w[j] = (short)(hb >> 16);
    }
    const int chunk = k >> 6, wvv = (k >> 4) & 3, colc = k & 15;
    *(short8*)((char*)cbh + chunk * 16384 + wvv * 4096 + (g >> 2) * 1024 +
               (g & 3) * 256 + colc * 16) = w;
  } else if (bid < 136) {
    const int k = (bid - 128) * 256 + tid;        // 2048 codes
    counts[k] = 0;
    if (tid < 32) part[(bid - 128) * 32 + tid] = 0.0;  // zero rescore-era slots
    const float* p = cb + (size_t)k * Dd;
    float r[8];
    #pragma unroll
    for (int j = 0; j < 8; ++j) r[j] = __fmul_rn(p[j], p[j]);
    for (int i = 1; i < 16; ++i) {
      #pragma unroll
      for (int j = 0; j < 8; ++j) {
        const float v = p[8 * i + j];
        r[j] = __fadd_rn(r[j], __fmul_rn(v, v));
      }
    }
    e2f[k] = __fadd_rn(__fadd_rn(__fadd_rn(r[0], r[1]), __fadd_rn(r[2], r[3])),
                       __fadd_rn(__fadd_rn(r[4], r[5]), __fadd_rn(r[6], r[7])));
  } else {
    const int g = (bid - 136) * 256 + tid;        // 65536 rows
    const int b = g >> 10, t = g & 1023;
    const float* p = z + (size_t)b * DT + t;      // x_d = p[d*Tt]
    float r[8];
    #pragma unroll
    for (int j = 0; j < 8; ++j) {
      const float v = p[j * Tt];
      r[j] = __fmul_rn(v, v);
    }
    for (int i = 1; i < 16; ++i) {
      #pragma unroll
      for (int j = 0; j < 8; ++j) {
        const float v = p[(8 * i + j) * Tt];
        r[j] = __fadd_rn(r[j], __fmul_rn(v, v));
      }
    }
    Arow[g] = __fadd_rn(__fadd_rn(__fadd_rn(r[0], r[1]), __fadd_rn(r[2], r[3])),
                        __fadd_rn(__fadd_rn(r[4], r[5]), __fadd_rn(r[6], r[7])));
  }
}

// key(s): monotone u32 map of float s (no NaNs here). pk = (key&~31)|it embeds
// the chunk id; u32 order == (s, it) lexicographic within 32-ulp truncation.
__device__ __forceinline__ unsigned skey(float s) {
  const unsigned u = __float_as_uint(s);
  return u ^ ((unsigned)(((int)u) >> 31) | 0x80000000u);
}
__device__ __forceinline__ float unkey(unsigned k) {
  const unsigned k2 = k & 0xFFFFFFE0u;
  const unsigned u = (k2 & 0x80000000u) ? (k2 ^ 0x80000000u) : ~k2;
  return __uint_as_float(u);
}

// Phase 1: SINGLE-sweep hi-plane bf16 MFMA scoring with in-register top-2
// candidate tracking (replaces the two-sweep recompute; halves MFMA+VALU).
// 128 rows/block (512 blocks), 4 waves = 2 row-halves (wr) x 2 col-halves
// (wc); each wave owns 64 rows x 32 cols of each 64-code chunk. A (z rows,
// bf16-hi) in VGPRs; B global->VGPR from SOA cbh (coalesced 1KB loads,
// 1-deep prefetch). Per (lane,slot) [32 slots = 4rt x 2ct x 4r] track the
// two smallest packed keys pk=(sortable(s)&~31)|chunk.
// Post-loop: exact row-global min (u32 min of v1 == min of same fmaf s
// values), thr = min + marg_row + 2e-6 (slack covers 32-ulp truncation ->
// candidate set remains a superset of {s < min+marg}). Append each slot's
// v1 if below thr; if a slot's v2 also passes, a hidden 3rd code on that
// slot is possible -> bump cnt by 64 -> candcnt>16 -> exact fallback.
// Winner is always some slot's v1 -> c>=1 for clean rows.
__global__ __launch_bounds__(256, 2)
void score_kernel(const float* __restrict__ z, const ushort* __restrict__ cbh,
                  const float* __restrict__ e2f, const float* __restrict__ Arow,
                  ushort* __restrict__ cand_g, int* __restrict__ candcnt) {
  __shared__ __attribute__((aligned(16))) ushort zh[16384]; // 32KB z hi plane
  __shared__ float margL[128];
  __shared__ unsigned sredU[256];    // [row][wc] partial min keys
  __shared__ float thrF[128];
  __shared__ int cntL[128];
  __shared__ ushort candL[128 * 16]; // 4KB

  const int tid = threadIdx.x;
  const int n0 = blockIdx.x * 128;               // 512 blocks
  const int b = n0 >> 10, t0 = n0 & 1023;
  const float* zb = z + (size_t)b * DT + t0;
  const int lane = tid & 63, wv = tid >> 6;
  const int col = lane & 15, quad = lane >> 4;
  const int wr = wv >> 1, wc = wv & 1;

  // ---- prologue: stage z hi plane (128 rows x 128 d, 16B-granule swizzled) ----
  {
    const int i = tid & 127;          // row in block
    const int half = tid >> 7;        // 0/1
    #pragma unroll
    for (int g8 = 0; g8 < 8; ++g8) {
      const int gran = half * 8 + g8;
      short8 w;
      #pragma unroll
      for (int j = 0; j < 8; ++j) {
        const int d = gran * 8 + j;
        const float v = zb[d * Tt + i];            // coalesced over i
        const unsigned u = __float_as_uint(v);
        const unsigned hb = (u + 0x7FFFu + ((u >> 16) & 1u)) & 0xFFFF0000u;
        w[j] = (short)(hb >> 16);
      }
      *(short8*)&zh[i * 128 + ((gran ^ (i & 15)) << 3)] = w;
    }
  }
  if (tid < 128) {
    margL[tid] = 8.7e-5f * sqrtf(Arow[n0 + tid]) + 1.0e-4f;
    cntL[tid] = 0;
  }
  __syncthreads();

  // ---- A fragments into registers (64 rows per wave, K=128) ----
  short8 afr[4][4];
  #pragma unroll
  for (int rt = 0; rt < 4; ++rt)
    #pragma unroll
    for (int ks = 0; ks < 4; ++ks) {
      const int rw = wr * 64 + rt * 16 + col;     // rw&15 == col
      afr[rt][ks] = *(const short8*)&zh[rw * 128 + (((ks * 4 + quad) ^ col) << 3)];
    }

  // per-lane B base in SOA layout: wc half + lane*16B; frag(ct,ks) at
  // +ct*4096B +ks*1024B; chunk stride 16384B (=8192 ushorts)
  const ushort* const bp0 = cbh + wc * 4096 + lane * 8;   // ushort units
  const float* const ep0 = e2f + wc * 32 + col;

  const float4v vzero = {0.f, 0.f, 0.f, 0.f};
  unsigned v1pk[32], v2pk[32];
  #pragma unroll
  for (int sl = 0; sl < 32; ++sl) { v1pk[sl] = 0xFFFFFFFFu; v2pk[sl] = 0xFFFFFFFFu; }

  // ---- single sweep: score + top-2 tracking (barrier-free) ----
  {
    const ushort* bp = bp0;
    const float* ep = ep0;
    short8 bb[2][4];
    #pragma unroll
    for (int ct = 0; ct < 2; ++ct)
      #pragma unroll
      for (int ks = 0; ks < 4; ++ks)
        bb[ct][ks] = *(const short8*)(bp + ct * 2048 + ks * 512);
    float e2v[2] = {ep[0], ep[16]};
    for (int it = 0; it < 32; ++it) {
      const int adv = (it < 31) ? 8192 : 0;       // prefetch next chunk (clamped)
      const int eadv = (it < 31) ? 64 : 0;
      short8 nb[2][4];
      #pragma unroll
      for (int ct = 0; ct < 2; ++ct)
        #pragma unroll
        for (int ks = 0; ks < 4; ++ks)
          nb[ct][ks] = *(const short8*)(bp + adv + ct * 2048 + ks * 512);
      const float ne2[2] = {ep[eadv], ep[eadv + 16]};
      float4v acc[4][2];
      #pragma unroll
      for (int rt = 0; rt < 4; ++rt) { acc[rt][0] = vzero; acc[rt][1] = vzero; }
      #pragma unroll
      for (int ks = 0; ks < 4; ++ks)
        #pragma unroll
        for (int rt = 0; rt < 4; ++rt) {
          acc[rt][0] = __builtin_amdgcn_mfma_f32_16x16x32_bf16(afr[rt][ks], bb[0][ks], acc[rt][0], 0, 0, 0);
          acc[rt][1] = __builtin_amdgcn_mfma_f32_16x16x32_bf16(afr[rt][ks], bb[1][ks], acc[rt][1], 0, 0, 0);
        }
      #pragma unroll
      for (int rt = 0; rt < 4; ++rt)
        #pragma unroll
        for (int ct = 0; ct < 2; ++ct)
          #pragma unroll
          for (int r = 0; r < 4; ++r) {
            const float s = fmaf(-2.0f, acc[rt][ct][r], e2v[ct]);  // same values as verified sweeps
            const unsigned pk = (skey(s) & 0xFFFFFFE0u) | (unsigned)it;
            const int sl = rt * 8 + ct * 4 + r;
            const unsigned old1 = v1pk[sl];
            const unsigned dis = (pk < old1) ? old1 : pk;   // displaced (max)
            v1pk[sl] = (pk < old1) ? pk : old1;             // min
            v2pk[sl] = (dis < v2pk[sl]) ? dis : v2pk[sl];
          }
      #pragma unroll
      for (int ct = 0; ct < 2; ++ct)
        #pragma unroll
        for (int ks = 0; ks < 4; ++ks) bb[ct][ks] = nb[ct][ks];
      e2v[0] = ne2[0]; e2v[1] = ne2[1];
      bp += 8192;
      ep += 64;
    }
  }

  // ---- exact row-global min reduce: ct pair + 16 cols (shfl) + 2 wc (LDS) ----
  #pragma unroll
  for (int rt = 0; rt < 4; ++rt)
    #pragma unroll
    for (int r = 0; r < 4; ++r) {
      unsigned v = v1pk[rt * 8 + r] < v1pk[rt * 8 + 4 + r] ? v1pk[rt * 8 + r]
                                                           : v1pk[rt * 8 + 4 + r];
      #pragma unroll
      for (int o = 1; o < 16; o <<= 1) {
        const unsigned w = (unsigned)__shfl_xor((int)v, o, 64);
        v = w < v ? w : v;
      }
      if (col == 0) {
        const int row = wr * 64 + rt * 16 + quad * 4 + r;
        sredU[row * 2 + wc] = v;
      }
    }
  __syncthreads();
  if (tid < 128) {
    const unsigned mk = sredU[tid * 2] < sredU[tid * 2 + 1] ? sredU[tid * 2]
                                                            : sredU[tid * 2 + 1];
    // min of truncated keys <= true min; +2e-6 slack keeps superset property
    thrF[tid] = unkey(mk) + margL[tid] + 2.0e-6f;
  }
  __syncthreads();

  // ---- append slot winners; flag rows where a slot's v2 also qualifies ----
  float thrS[16];
  #pragma unroll
  for (int rt = 0; rt < 4; ++rt)
    #pragma unroll
    for (int r = 0; r < 4; ++r)
      thrS[rt * 4 + r] = thrF[wr * 64 + rt * 16 + quad * 4 + r];
  #pragma unroll
  for (int rt = 0; rt < 4; ++rt)
    #pragma unroll
    for (int ct = 0; ct < 2; ++ct)
      #pragma unroll
      for (int r = 0; r < 4; ++r) {
        const int sl = rt * 8 + ct * 4 + r;
        const float thr = thrS[rt * 4 + r];
        const int row = wr * 64 + rt * 16 + quad * 4 + r;
        if (unkey(v1pk[sl]) < thr) {
          const int pos = atomicAdd(&cntL[row], 1);
          if (pos < 16)
            candL[row * 16 + pos] =
                (ushort)((v1pk[sl] & 31u) * 64 + wc * 32 + ct * 16 + col);
        }
        if (unkey(v2pk[sl]) < thr) atomicAdd(&cntL[row], 64);  // force fallback
      }
  __syncthreads();
  if (tid < 128) {
    const int n = n0 + tid;
    candcnt[n] = cntL[tid];
    uint4* dst = (uint4*)(cand_g + (size_t)n * 16);
    const uint4* src = (const uint4*)(candL + tid * 16);
    dst[0] = src[0];
    dst[1] = src[1];
  }
}

// Phase 2: exact np-replica rescore (R2-verified formula). Loss lives in
// gather_kernel (coalesced z there); this kernel only picks the winner.
__global__ __launch_bounds__(256)
void rescore_kernel(const float* __restrict__ z, const float* __restrict__ cb,
                    const float* __restrict__ e2f, const float* __restrict__ Arow,
                    const ushort* __restrict__ cand_g, const int* __restrict__ candcnt,
                    int* __restrict__ idxbuf, int* __restrict__ counts,
                    float* __restrict__ out_idx) {
  const int tid = threadIdx.x;
  const int n = blockIdx.x * 256 + tid;           // 256 blocks
  const int c = candcnt[n];
  if (c >= 1 && c <= 16) {                        // fallback handles the rest
    const int b = n >> 10, t = n & 1023;
    const float* zb = z + (size_t)b * DT + t;
    const float A = Arow[n];
    float best = 1e30f;
    int bk = Kk;
    for (int j = 0; j < c; ++j) {
      const int k = cand_g[(size_t)n * 16 + j];
      const float* e = cb + (size_t)k * Dd;
      double acc = 0.0;
      #pragma unroll 8
      for (int d = 0; d < 128; d += 4) {
        const float4 ev = *(const float4*)(e + d);
        acc += (double)zb[(d + 0) * Tt] * (double)ev.x;
        acc += (double)zb[(d + 1) * Tt] * (double)ev.y;
        acc += (double)zb[(d + 2) * Tt] * (double)ev.z;
        acc += (double)zb[(d + 3) * Tt] * (double)ev.w;
      }
      const float m32 = (float)acc;
      const float X = __fsub_rn(A, __fmul_rn(2.0f, m32));
      const float Dq = __fadd_rn(X, e2f[k]);
      if (Dq < best || (Dq == best && k < bk)) { best = Dq; bk = k; }
    }
    idxbuf[n] = bk;
    out_idx[n] = (float)bk;
    atomicAdd(&counts[bk], 1);
  }
}

// Fallback: full exact scan for rows with empty/overflowed/flagged lists.
__global__ __launch_bounds__(256)
void fallback_kernel(const float* __restrict__ z, const float* __restrict__ cb,
                     const float* __restrict__ e2f, const float* __restrict__ Arow,
                     const int* __restrict__ candcnt, int* __restrict__ idxbuf,
                     int* __restrict__ counts, float* __restrict__ out_idx,
                     double* __restrict__ part) {
  __shared__ int flags[256];
  __shared__ int nf;
  __shared__ float xrow[128];
  __shared__ float rs[256];
  __shared__ int rk[256];
  const int tid = threadIdx.x;
  const int nb = blockIdx.x * 256;                // 256 blocks
  if (tid == 0) { nf = 0; part[256 + blockIdx.x] = 0.0; }
  __syncthreads();
  const int c = candcnt[nb + tid];
  const int bad = (c < 1 || c > 16) ? 1 : 0;
  flags[tid] = bad;
  if (bad) atomicAdd(&nf, 1);
  __syncthreads();
  if (nf == 0) return;                            // fast path
  for (int rr = 0; rr < 256; ++rr) {
    if (!flags[rr]) continue;                     // block-uniform
    const int n = nb + rr;
    const int b = n >> 10, t = n & 1023;
    if (tid < 128) xrow[tid] = z[(size_t)b * DT + (size_t)tid * Tt + t];
    __syncthreads();
    const float A = Arow[n];
    float best = 1e30f;
    int bk = Kk;
    for (int kk = tid * 8; kk < tid * 8 + 8; ++kk) {
      const float* e = cb + (size_t)kk * Dd;
      double acc = 0.0;
      for (int d = 0; d < 128; d += 4) {
        const float4 ev = *(const float4*)(e + d);
        acc += (double)xrow[d + 0] * (double)ev.x;
        acc += (double)xrow[d + 1] * (double)ev.y;
        acc += (double)xrow[d + 2] * (double)ev.z;
        acc += (double)xrow[d + 3] * (double)ev.w;
      }
      const float m32 = (float)acc;
      const float Dq = __fadd_rn(__fsub_rn(A, __fmul_rn(2.0f, m32)), e2f[kk]);
      if (Dq < best || (Dq == best && kk < bk)) { best = Dq; bk = kk; }
    }
    rs[tid] = best;
    rk[tid] = bk;
    __syncthreads();
    for (int o = 128; o > 0; o >>= 1) {
      if (tid < o) {
        if (rs[tid + o] < rs[tid] || (rs[tid + o] == rs[tid] && rk[tid + o] < rk[tid])) {
          rs[tid] = rs[tid + o];
          rk[tid] = rk[tid + o];
        }
      }
      __syncthreads();
    }
    if (tid == 0) {
      const int w = rk[0];
      idxbuf[n] = w;
      out_idx[n] = (float)w;
      atomicAdd(&counts[w], 1);
    }
    __syncthreads();
  }
}

// Gather z_q into (B,D,T) layout + commitment-loss partials (coalesced z).
__global__ __launch_bounds__(256)
void gather_kernel(const float* __restrict__ cb, const int* __restrict__ idxbuf,
                   const float* __restrict__ z, float* __restrict__ out0,
                   double* __restrict__ part) {
  const int tid = threadIdx.x;
  const size_t o0 = ((size_t)blockIdx.x * 256 + tid) * 8;  // 4096 blocks
  const int b = (int)(o0 >> 17);
  const int dt = (int)(o0 & (size_t)(DT - 1));
  const int d = dt >> 10;
  const int t = dt & 1023;
  const int n = (b << 10) + t;
  float q[8];
  #pragma unroll
  for (int j = 0; j < 8; ++j) q[j] = cb[(size_t)idxbuf[n + j] * Dd + d];
  const float4 z0 = *(const float4*)(z + o0);
  const float4 z1 = *(const float4*)(z + o0 + 4);
  *(float4*)(out0 + o0)     = make_float4(q[0], q[1], q[2], q[3]);
  *(float4*)(out0 + o0 + 4) = make_float4(q[4], q[5], q[6], q[7]);
  double sq = 0.0;
  {
    const float zz[8] = {z0.x, z0.y, z0.z, z0.w, z1.x, z1.y, z1.z, z1.w};
    #pragma unroll
    for (int j = 0; j < 8; ++j) {
      const double dif = (double)zz[j] - (double)q[j];
      sq += dif * dif;
    }
  }
  #pragma unroll
  for (int o = 32; o > 0; o >>= 1) sq += __shfl_down(sq, o, 64);
  __shared__ double w4[4];
  if ((tid & 63) == 0) w4[tid >> 6] = sq;
  __syncthreads();
  if (tid == 0) atomicAdd(&part[256 + (blockIdx.x & 255)], w4[0] + w4[1] + w4[2] + w4[3]);
}

__global__ __launch_bounds__(256)
void finalize_kernel(const int* __restrict__ counts, const double* __restrict__ part,
                     float* __restrict__ out) {
  const int tid = threadIdx.x;
  __shared__ double red[256];
  double s = 0.0;
  for (int i = tid; i < 512; i += 256) s += part[i];
  red[tid] = s;
  __syncthreads();
  for (int o = 128; o > 0; o >>= 1) {
    if (tid < o) red[tid] += red[tid + o];
    __syncthreads();
  }
  const double loss = red[0];
  __syncthreads();
  double e = 0.0;
  for (int k = tid; k < 2048; k += 256) {
    const double p = (double)counts[k] / 65536.0;
    e += p * log(p + 1e-10);
  }
  red[tid] = e;
  __syncthreads();
  for (int o = 128; o > 0; o >>= 1) {
    if (tid < o) red[tid] += red[tid + o];
    __syncthreads();
  }
  if (tid == 0) {
    out[8388608] = (float)(0.25 * loss / 8388608.0);
    out[8388609] = (float)exp(-red[0]);
  }
}

extern "C" void kernel_launch(void* const* d_in, const int* in_sizes, int n_in,
                              void* d_out, int out_size, void* d_ws, size_t ws_size,
                              hipStream_t stream) {
  const float* z = (const float*)d_in[0];      // (B, D, T) fp32
  const float* cb = (const float*)d_in[1];     // (K, D) fp32
  float* out = (float*)d_out;                  // [z_q (8388608) | loss | perp | idx (65536)]
  char* ws = (char*)d_ws;
  ushort* cbh    = (ushort*)ws;
  float* e2f     = (float*)(ws + 524288);
  float* Arow    = (float*)(ws + 532480);
  int* idxbuf    = (int*)(ws + 794624);
  int* counts    = (int*)(ws + 1056768);
  double* part   = (double*)(ws + 1064960);
  ushort* cand_g = (ushort*)(ws + 1069056);
  int* candcnt   = (int*)(ws + 3166208);

  hipLaunchKernelGGL(setup_kernel,    dim3(392),  dim3(256), 0, stream, cb, z, cbh, e2f, Arow,
                     counts, part);
  hipLaunchKernelGGL(score_kernel,    dim3(512),  dim3(256), 0, stream, z, cbh, e2f, Arow,
                     cand_g, candcnt);
  hipLaunchKernelGGL(rescore_kernel,  dim3(256),  dim3(256), 0, stream, z, cb, e2f, Arow,
                     cand_g, candcnt, idxbuf, counts, out + 8388610);
  hipLaunchKernelGGL(fallback_kernel, dim3(256),  dim3(256), 0, stream, z, cb, e2f, Arow,
                     candcnt, idxbuf, counts, out + 8388610, part);
  hipLaunchKernelGGL(gather_kernel,   dim3(4096), dim3(256), 0, stream, cb, idxbuf, z, out, part);
  hipLaunchKernelGGL(finalize_kernel, dim3(1),    dim3(256), 0, stream, counts, part, out);
}

// Round 6
// 251.928 us; speedup vs baseline: 2.5073x; 2.5073x over previous
//
#include <hip/hip_runtime.h>
#include <math.h>

#define Dd 128
#define Tt 1024
#define Kk 2048
#define Nn 65536
#define DT 131072  // Dd*Tt

typedef __attribute__((ext_vector_type(8))) short short8;
typedef __attribute__((ext_vector_type(4))) float float4v;

// ws layout (bytes):
//   cbh     @ 0        : ushort[262144] = 524288   (bf16 hi plane of codebook, SOA-fragment layout)
//   e2f     @ 524288   : float[2048]    = 8192     (np-replica fp32 ||e||^2)
//   Arow    @ 532480   : float[65536]   = 262144   (np-replica fp32 ||x||^2, written by score_kernel)
//   idxbuf  @ 794624   : int[65536]     = 262144
//   counts  @ 1056768  : int[2048]      = 8192
//   part    @ 1064960  : double[512]    = 4096
//   cand_g  @ 1069056  : ushort[65536*16] = 2097152
//   candcnt @ 3166208  : int[65536]     = 262144
// total 3428352 B (~3.43 MB)
//
// cbh SOA layout: for code k, 16B granule g (g of the 256B row):
//   chunk=k>>6, wv=(k>>4)&3, col=k&15, ks=g>>2, quad=g&3
//   byte dest = chunk*16384 + wv*4096 + ks*1024 + quad*256 + col*16
// => score_kernel per-(wave,iter,ks) B-fragment load is lane*16B contiguous (1 KB).

// Setup: SOA bf16-hi split of codebook (blocks 0..127) + np-replica fp32
// ||e||^2 / counts-zero (blocks 128..135). z passes moved into score_kernel.
__global__ __launch_bounds__(256)
void setup_kernel(const float* __restrict__ cb, ushort* __restrict__ cbh,
                  float* __restrict__ e2f, int* __restrict__ counts) {
  const int bid = blockIdx.x, tid = threadIdx.x;
  if (bid < 128) {
    const int gi = bid * 256 + tid;               // 32768 granules (16B each)
    const int k = gi >> 4, g = gi & 15;
    const float* p = cb + (size_t)k * Dd + g * 8; // 32B coalesced read
    short8 w;
    #pragma unroll
    for (int j = 0; j < 8; ++j) {
      const unsigned u = __float_as_uint(p[j]);
      const unsigned hb = (u + 0x7FFFu + ((u >> 16) & 1u)) & 0xFFFF0000u;  // RNE bf16
      w[j] = (short)(hb >> 16);
    }
    const int chunk = k >> 6, wvv = (k >> 4) & 3, colc = k & 15;
    *(short8*)((char*)cbh + chunk * 16384 + wvv * 4096 + (g >> 2) * 1024 +
               (g & 3) * 256 + colc * 16) = w;
  } else {
    const int k = (bid - 128) * 256 + tid;        // 2048 codes
    counts[k] = 0;
    const float* p = cb + (size_t)k * Dd;
    float r[8];
    #pragma unroll
    for (int j = 0; j < 8; ++j) r[j] = __fmul_rn(p[j], p[j]);
    for (int i = 1; i < 16; ++i) {
      #pragma unroll
      for (int j = 0; j < 8; ++j) {
        const float v = p[8 * i + j];
        r[j] = __fadd_rn(r[j], __fmul_rn(v, v));
      }
    }
    e2f[k] = __fadd_rn(__fadd_rn(__fadd_rn(r[0], r[1]), __fadd_rn(r[2], r[3])),
                       __fadd_rn(__fadd_rn(r[4], r[5]), __fadd_rn(r[6], r[7])));
  }
}

// Phase 1: two-sweep hi-plane bf16 MFMA scoring (verified semantics), tuned
// for occupancy: 64 rows/block (1024 blocks), 4 waves; each wave owns all 64
// rows and a 16-col slice of each 64-code chunk -> afr[4][4] (64 VGPR) + 16
// MFMA/iter/wave; ~140 VGPR total -> 3 waves/SIMD (launch_bounds(256,3)),
// 3 blocks/CU co-resident to hide B-load latency under MFMA.
// Also computes Arow (np-order fp32 ||x||^2, bitwise = old setup pass) in
// the prologue from L1-hot z and writes it for rescore.
// Sweep A: per-lane running min -> shfl over 16 cols -> LDS reduce over 4
// waves -> exact row-global min m. Sweep B: bitwise-identical recompute,
// append codes with s < m + marg_row (marg_row = 8.7e-5*sqrt(Arow)+1e-4).
// Cap 16; candcnt>16 or 0 -> exact fallback (expected: none).
__global__ __launch_bounds__(256, 3)
void score_kernel(const float* __restrict__ z, const ushort* __restrict__ cbh,
                  const float* __restrict__ e2f, float* __restrict__ Arow,
                  ushort* __restrict__ cand_g, int* __restrict__ candcnt) {
  __shared__ __attribute__((aligned(16))) ushort zh[8192]; // 16KB z hi plane (64x128)
  __shared__ float margL[64];
  __shared__ float sredA[256];       // [row][wv]
  __shared__ float thrF[64];
  __shared__ int cntL[64];
  __shared__ ushort candL[64 * 16];  // 2KB

  const int tid = threadIdx.x;
  const int n0 = blockIdx.x * 64;                // 1024 blocks
  const int b = n0 >> 10, t0 = n0 & 1023;
  const float* zb = z + (size_t)b * DT + t0;
  const int lane = tid & 63, wv = tid >> 6;
  const int col = lane & 15, quad = lane >> 4;

  // ---- prologue: stage z hi plane (64 rows x 128 d, 16B-granule swizzled) ----
  {
    const int i = tid & 63;           // row in block
    const int half = tid >> 6;        // 0..3
    #pragma unroll
    for (int g4 = 0; g4 < 4; ++g4) {
      const int gran = half * 4 + g4;
      short8 w;
      #pragma unroll
      for (int j = 0; j < 8; ++j) {
        const int d = gran * 8 + j;
        const float v = zb[d * Tt + i];            // coalesced over i
        const unsigned u = __float_as_uint(v);
        const unsigned hb = (u + 0x7FFFu + ((u >> 16) & 1u)) & 0xFFFF0000u;
        w[j] = (short)(hb >> 16);
      }
      *(short8*)&zh[i * 128 + ((gran ^ (i & 15)) << 3)] = w;
    }
  }
  // ---- Arow: np-pairwise fp32 ||x||^2 (bitwise = old setup pass; z L1-hot) ----
  if (tid < 64) {
    const float* p = zb + tid;                    // x_d = p[d*Tt]
    float r[8];
    #pragma unroll
    for (int j = 0; j < 8; ++j) {
      const float v = p[j * Tt];
      r[j] = __fmul_rn(v, v);
    }
    for (int i = 1; i < 16; ++i) {
      #pragma unroll
      for (int j = 0; j < 8; ++j) {
        const float v = p[(8 * i + j) * Tt];
        r[j] = __fadd_rn(r[j], __fmul_rn(v, v));
      }
    }
    const float A = __fadd_rn(__fadd_rn(__fadd_rn(r[0], r[1]), __fadd_rn(r[2], r[3])),
                              __fadd_rn(__fadd_rn(r[4], r[5]), __fadd_rn(r[6], r[7])));
    Arow[n0 + tid] = A;
    margL[tid] = 8.7e-5f * sqrtf(A) + 1.0e-4f;
    cntL[tid] = 0;
  }
  __syncthreads();

  // ---- A fragments into registers (all 64 rows per wave, K=128) ----
  short8 afr[4][4];
  #pragma unroll
  for (int rt = 0; rt < 4; ++rt)
    #pragma unroll
    for (int ks = 0; ks < 4; ++ks) {
      const int rw = rt * 16 + col;               // rw&15 == col
      afr[rt][ks] = *(const short8*)&zh[rw * 128 + (((ks * 4 + quad) ^ col) << 3)];
    }

  // per-lane B base in SOA layout: wave slice + lane*16B; frag ks at +1024B;
  // chunk stride 16384B (=8192 ushorts)
  const ushort* const bp0 = cbh + wv * 2048 + lane * 8;   // ushort units
  const float* const ep0 = e2f + wv * 16 + col;

  const float4v vzero = {0.f, 0.f, 0.f, 0.f};
  float rmin[16];
  #pragma unroll
  for (int sl = 0; sl < 16; ++sl) rmin[sl] = 1e30f;

  // ---- Sweep A: exact row-global min over bf16-hi scores (barrier-free) ----
  {
    const ushort* bp = bp0;
    const float* ep = ep0;
    short8 bb[4];
    #pragma unroll
    for (int ks = 0; ks < 4; ++ks) bb[ks] = *(const short8*)(bp + ks * 512);
    float e2v = *ep;
    for (int it = 0; it < 32; ++it) {
      const int adv = (it < 31) ? 8192 : 0;       // prefetch next chunk (clamped)
      const int eadv = (it < 31) ? 64 : 0;
      short8 nb[4];
      #pragma unroll
      for (int ks = 0; ks < 4; ++ks) nb[ks] = *(const short8*)(bp + adv + ks * 512);
      const float ne2 = ep[eadv];
      float4v acc[4];
      #pragma unroll
      for (int rt = 0; rt < 4; ++rt) acc[rt] = vzero;
      #pragma unroll
      for (int ks = 0; ks < 4; ++ks)
        #pragma unroll
        for (int rt = 0; rt < 4; ++rt)
          acc[rt] = __builtin_amdgcn_mfma_f32_16x16x32_bf16(afr[rt][ks], bb[ks], acc[rt], 0, 0, 0);
      #pragma unroll
      for (int rt = 0; rt < 4; ++rt)
        #pragma unroll
        for (int r = 0; r < 4; ++r) {
          const float s = fmaf(-2.0f, acc[rt][r], e2v);
          rmin[rt * 4 + r] = fminf(rmin[rt * 4 + r], s);
        }
      #pragma unroll
      for (int ks = 0; ks < 4; ++ks) bb[ks] = nb[ks];
      e2v = ne2;
      bp += 8192;
      ep += 64;
    }
  }

  // ---- exact row-global min reduce: 16 cols (shfl) x 4 waves (LDS) ----
  #pragma unroll
  for (int sl = 0; sl < 16; ++sl) {
    float v = rmin[sl];
    v = fminf(v, __shfl_xor(v, 1, 64));
    v = fminf(v, __shfl_xor(v, 2, 64));
    v = fminf(v, __shfl_xor(v, 4, 64));
    v = fminf(v, __shfl_xor(v, 8, 64));
    rmin[sl] = v;
  }
  if (col == 0) {
    #pragma unroll
    for (int sl = 0; sl < 16; ++sl) {
      const int rw = (sl >> 2) * 16 + quad * 4 + (sl & 3);
      sredA[rw * 4 + wv] = rmin[sl];
    }
  }
  __syncthreads();
  if (tid < 64) {
    const float m = fminf(fminf(sredA[tid * 4], sredA[tid * 4 + 1]),
                          fminf(sredA[tid * 4 + 2], sredA[tid * 4 + 3]));
    thrF[tid] = m + margL[tid];
  }
  __syncthreads();
  #pragma unroll
  for (int sl = 0; sl < 16; ++sl)       // reuse rmin regs as per-slot thresholds
    rmin[sl] = thrF[(sl >> 2) * 16 + quad * 4 + (sl & 3)];

  // ---- Sweep B: bitwise-identical recompute, exact-threshold append ----
  {
    const ushort* bp = bp0;
    const float* ep = ep0;
    short8 bb[4];
    #pragma unroll
    for (int ks = 0; ks < 4; ++ks) bb[ks] = *(const short8*)(bp + ks * 512);
    float e2v = *ep;
    for (int it = 0; it < 32; ++it) {
      const int adv = (it < 31) ? 8192 : 0;
      const int eadv = (it < 31) ? 64 : 0;
      short8 nb[4];
      #pragma unroll
      for (int ks = 0; ks < 4; ++ks) nb[ks] = *(const short8*)(bp + adv + ks * 512);
      const float ne2 = ep[eadv];
      float4v acc[4];
      #pragma unroll
      for (int rt = 0; rt < 4; ++rt) acc[rt] = vzero;
      #pragma unroll
      for (int ks = 0; ks < 4; ++ks)
        #pragma unroll
        for (int rt = 0; rt < 4; ++rt)
          acc[rt] = __builtin_amdgcn_mfma_f32_16x16x32_bf16(afr[rt][ks], bb[ks], acc[rt], 0, 0, 0);
      const int cbase = it * 64 + wv * 16 + col;
      #pragma unroll
      for (int rt = 0; rt < 4; ++rt)
        #pragma unroll
        for (int r = 0; r < 4; ++r) {
          const float s = fmaf(-2.0f, acc[rt][r], e2v);
          if (s < rmin[rt * 4 + r]) {
            const int rw = rt * 16 + quad * 4 + r;
            const int pos = atomicAdd(&cntL[rw], 1);
            if (pos < 16) candL[rw * 16 + pos] = (ushort)cbase;
          }
        }
      #pragma unroll
      for (int ks = 0; ks < 4; ++ks) bb[ks] = nb[ks];
      e2v = ne2;
      bp += 8192;
      ep += 64;
    }
  }
  __syncthreads();
  if (tid < 64) {
    const int n = n0 + tid;
    candcnt[n] = cntL[tid];
    uint4* dst = (uint4*)(cand_g + (size_t)n * 16);
    const uint4* src = (const uint4*)(candL + tid * 16);
    dst[0] = src[0];
    dst[1] = src[1];
  }
}

// Phase 2: exact np-replica rescore + f64 commitment-loss partial via
// loss_row = A - 2*dot_win + e2[win] (f64; dot already computed for winner).
__global__ __launch_bounds__(256)
void rescore_kernel(const float* __restrict__ z, const float* __restrict__ cb,
                    const float* __restrict__ e2f, const float* __restrict__ Arow,
                    const ushort* __restrict__ cand_g, const int* __restrict__ candcnt,
                    int* __restrict__ idxbuf, int* __restrict__ counts,
                    float* __restrict__ out_idx, double* __restrict__ part) {
  const int tid = threadIdx.x;
  const int n = blockIdx.x * 256 + tid;           // 256 blocks
  const int c = candcnt[n];
  double sq = 0.0;
  if (c >= 1 && c <= 16) {                        // fallback handles the rest
    const int b = n >> 10, t = n & 1023;
    const float* zb = z + (size_t)b * DT + t;
    const float A = Arow[n];
    float best = 1e30f;
    int bk = Kk;
    double bacc = 0.0;
    for (int j = 0; j < c; ++j) {
      const int k = cand_g[(size_t)n * 16 + j];
      const float* e = cb + (size_t)k * Dd;
      double acc = 0.0;
      #pragma unroll 8
      for (int d = 0; d < 128; d += 4) {
        const float4 ev = *(const float4*)(e + d);
        acc += (double)zb[(d + 0) * Tt] * (double)ev.x;
        acc += (double)zb[(d + 1) * Tt] * (double)ev.y;
        acc += (double)zb[(d + 2) * Tt] * (double)ev.z;
        acc += (double)zb[(d + 3) * Tt] * (double)ev.w;
      }
      const float m32 = (float)acc;
      const float X = __fsub_rn(A, __fmul_rn(2.0f, m32));
      const float Dq = __fadd_rn(X, e2f[k]);
      if (Dq < best || (Dq == best && k < bk)) { best = Dq; bk = k; bacc = acc; }
    }
    idxbuf[n] = bk;
    out_idx[n] = (float)bk;
    atomicAdd(&counts[bk], 1);
    sq = (double)A - 2.0 * bacc + (double)e2f[bk];
  }
  #pragma unroll
  for (int o = 32; o > 0; o >>= 1) sq += __shfl_down(sq, o, 64);
  __shared__ double w4[4];
  if ((tid & 63) == 0) w4[tid >> 6] = sq;
  __syncthreads();
  if (tid == 0) part[blockIdx.x] = w4[0] + w4[1] + w4[2] + w4[3];
}

// Fallback: full exact scan for rows with empty/overflowed lists (expected:
// none). Contributes those rows' loss into part[256..511].
__global__ __launch_bounds__(256)
void fallback_kernel(const float* __restrict__ z, const float* __restrict__ cb,
                     const float* __restrict__ e2f, const float* __restrict__ Arow,
                     const int* __restrict__ candcnt, int* __restrict__ idxbuf,
                     int* __restrict__ counts, float* __restrict__ out_idx,
                     double* __restrict__ part) {
  __shared__ int flags[256];
  __shared__ int nf;
  __shared__ float xrow[128];
  __shared__ float rs[256];
  __shared__ int rk[256];
  const int tid = threadIdx.x;
  const int nb = blockIdx.x * 256;                // 256 blocks
  if (tid == 0) { nf = 0; part[256 + blockIdx.x] = 0.0; }
  __syncthreads();
  const int c = candcnt[nb + tid];
  const int bad = (c < 1 || c > 16) ? 1 : 0;
  flags[tid] = bad;
  if (bad) atomicAdd(&nf, 1);
  __syncthreads();
  if (nf == 0) return;                            // fast path
  double bsum = 0.0;
  for (int rr = 0; rr < 256; ++rr) {
    if (!flags[rr]) continue;                     // block-uniform
    const int n = nb + rr;
    const int b = n >> 10, t = n & 1023;
    if (tid < 128) xrow[tid] = z[(size_t)b * DT + (size_t)tid * Tt + t];
    __syncthreads();
    const float A = Arow[n];
    float best = 1e30f;
    int bk = Kk;
    for (int kk = tid * 8; kk < tid * 8 + 8; ++kk) {
      const float* e = cb + (size_t)kk * Dd;
      double acc = 0.0;
      for (int d = 0; d < 128; d += 4) {
        const float4 ev = *(const float4*)(e + d);
        acc += (double)xrow[d + 0] * (double)ev.x;
        acc += (double)xrow[d + 1] * (double)ev.y;
        acc += (double)xrow[d + 2] * (double)ev.z;
        acc += (double)xrow[d + 3] * (double)ev.w;
      }
      const float m32 = (float)acc;
      const float Dq = __fadd_rn(__fsub_rn(A, __fmul_rn(2.0f, m32)), e2f[kk]);
      if (Dq < best || (Dq == best && kk < bk)) { best = Dq; bk = kk; }
    }
    rs[tid] = best;
    rk[tid] = bk;
    __syncthreads();
    for (int o = 128; o > 0; o >>= 1) {
      if (tid < o) {
        if (rs[tid + o] < rs[tid] || (rs[tid + o] == rs[tid] && rk[tid + o] < rk[tid])) {
          rs[tid] = rs[tid + o];
          rk[tid] = rk[tid + o];
        }
      }
      __syncthreads();
    }
    if (tid == 0) {
      const int w = rk[0];
      idxbuf[n] = w;
      out_idx[n] = (float)w;
      atomicAdd(&counts[w], 1);
      const float* ew = cb + (size_t)w * Dd;
      for (int d = 0; d < 128; ++d) {
        const double dif = (double)xrow[d] - (double)ew[d];
        bsum += dif * dif;
      }
    }
    __syncthreads();
  }
  if (tid == 0) part[256 + blockIdx.x] = bsum;
}

// Gather z_q into (B,D,T) layout (pure gather; loss handled in rescore).
__global__ __launch_bounds__(256)
void gather_kernel(const float* __restrict__ cb, const int* __restrict__ idxbuf,
                   float* __restrict__ out0) {
  const int tid = threadIdx.x;
  const size_t o0 = ((size_t)blockIdx.x * 256 + tid) * 8;  // 4096 blocks
  const int b = (int)(o0 >> 17);
  const int dt = (int)(o0 & (size_t)(DT - 1));
  const int d = dt >> 10;
  const int t = dt & 1023;
  const int n = (b << 10) + t;
  float q[8];
  #pragma unroll
  for (int j = 0; j < 8; ++j) q[j] = cb[(size_t)idxbuf[n + j] * Dd + d];
  *(float4*)(out0 + o0)     = make_float4(q[0], q[1], q[2], q[3]);
  *(float4*)(out0 + o0 + 4) = make_float4(q[4], q[5], q[6], q[7]);
}

__global__ __launch_bounds__(256)
void finalize_kernel(const int* __restrict__ counts, const double* __restrict__ part,
                     float* __restrict__ out) {
  const int tid = threadIdx.x;
  __shared__ double red[256];
  double s = 0.0;
  for (int i = tid; i < 512; i += 256) s += part[i];
  red[tid] = s;
  __syncthreads();
  for (int o = 128; o > 0; o >>= 1) {
    if (tid < o) red[tid] += red[tid + o];
    __syncthreads();
  }
  const double loss = red[0];
  __syncthreads();
  double e = 0.0;
  for (int k = tid; k < 2048; k += 256) {
    const double p = (double)counts[k] / 65536.0;
    e += p * log(p + 1e-10);
  }
  red[tid] = e;
  __syncthreads();
  for (int o = 128; o > 0; o >>= 1) {
    if (tid < o) red[tid] += red[tid + o];
    __syncthreads();
  }
  if (tid == 0) {
    out[8388608] = (float)(0.25 * loss / 8388608.0);
    out[8388609] = (float)exp(-red[0]);
  }
}

extern "C" void kernel_launch(void* const* d_in, const int* in_sizes, int n_in,
                              void* d_out, int out_size, void* d_ws, size_t ws_size,
                              hipStream_t stream) {
  const float* z = (const float*)d_in[0];      // (B, D, T) fp32
  const float* cb = (const float*)d_in[1];     // (K, D) fp32
  float* out = (float*)d_out;                  // [z_q (8388608) | loss | perp | idx (65536)]
  char* ws = (char*)d_ws;
  ushort* cbh    = (ushort*)ws;
  float* e2f     = (float*)(ws + 524288);
  float* Arow    = (float*)(ws + 532480);
  int* idxbuf    = (int*)(ws + 794624);
  int* counts    = (int*)(ws + 1056768);
  double* part   = (double*)(ws + 1064960);
  ushort* cand_g = (ushort*)(ws + 1069056);
  int* candcnt   = (int*)(ws + 3166208);

  hipLaunchKernelGGL(setup_kernel,    dim3(136),  dim3(256), 0, stream, cb, cbh, e2f, counts);
  hipLaunchKernelGGL(score_kernel,    dim3(1024), dim3(256), 0, stream, z, cbh, e2f, Arow,
                     cand_g, candcnt);
  hipLaunchKernelGGL(rescore_kernel,  dim3(256),  dim3(256), 0, stream, z, cb, e2f, Arow,
                     cand_g, candcnt, idxbuf, counts, out + 8388610, part);
  hipLaunchKernelGGL(fallback_kernel, dim3(256),  dim3(256), 0, stream, z, cb, e2f, Arow,
                     candcnt, idxbuf, counts, out + 8388610, part);
  hipLaunchKernelGGL(gather_kernel,   dim3(4096), dim3(256), 0, stream, cb, idxbuf, out);
  hipLaunchKernelGGL(finalize_kernel, dim3(1),    dim3(256), 0, stream, counts, part, out);
}

// Round 7
// 230.719 us; speedup vs baseline: 2.7378x; 1.0919x over previous
//
#include <hip/hip_runtime.h>
#include <math.h>

#define Dd 128
#define Tt 1024
#define Kk 2048
#define Nn 65536
#define DT 131072  // Dd*Tt

typedef __attribute__((ext_vector_type(8))) short short8;
typedef __attribute__((ext_vector_type(4))) float float4v;

// ws layout (bytes):
//   cbh     @ 0        : ushort[262144] = 524288   (bf16 hi plane of codebook, SOA-fragment layout)
//   e2f     @ 524288   : float[2048]    = 8192     (np-replica fp32 ||e||^2)
//   Arow    @ 532480   : float[65536]   = 262144   (np-replica fp32 ||x||^2, written by score_kernel)
//   idxbuf  @ 794624   : int[65536]     = 262144
//   counts  @ 1056768  : int[2048]      = 8192
//   part    @ 1064960  : double[512]    = 4096
//   cand_g  @ 1069056  : ushort[65536*16] = 2097152
//   candcnt @ 3166208  : int[65536]     = 262144
// total 3428352 B (~3.43 MB)
//
// cbh SOA layout: for code k, 16B granule g (g of the 256B row):
//   chunk=k>>6, wv=(k>>4)&3, col=k&15, ks=g>>2, quad=g&3
//   byte dest = chunk*16384 + wv*4096 + ks*1024 + quad*256 + col*16
// => score_kernel per-(wave,iter,ks) B-fragment load is lane*16B contiguous (1 KB).

// Setup: SOA bf16-hi split of codebook (blocks 0..127) + np-replica fp32
// ||e||^2 / counts-zero (blocks 128..135).
__global__ __launch_bounds__(256)
void setup_kernel(const float* __restrict__ cb, ushort* __restrict__ cbh,
                  float* __restrict__ e2f, int* __restrict__ counts) {
  const int bid = blockIdx.x, tid = threadIdx.x;
  if (bid < 128) {
    const int gi = bid * 256 + tid;               // 32768 granules (16B each)
    const int k = gi >> 4, g = gi & 15;
    const float* p = cb + (size_t)k * Dd + g * 8; // 32B coalesced read
    short8 w;
    #pragma unroll
    for (int j = 0; j < 8; ++j) {
      const unsigned u = __float_as_uint(p[j]);
      const unsigned hb = (u + 0x7FFFu + ((u >> 16) & 1u)) & 0xFFFF0000u;  // RNE bf16
      w[j] = (short)(hb >> 16);
    }
    const int chunk = k >> 6, wvv = (k >> 4) & 3, colc = k & 15;
    *(short8*)((char*)cbh + chunk * 16384 + wvv * 4096 + (g >> 2) * 1024 +
               (g & 3) * 256 + colc * 16) = w;
  } else {
    const int k = (bid - 128) * 256 + tid;        // 2048 codes
    counts[k] = 0;
    const float* p = cb + (size_t)k * Dd;
    float r[8];
    #pragma unroll
    for (int j = 0; j < 8; ++j) r[j] = __fmul_rn(p[j], p[j]);
    for (int i = 1; i < 16; ++i) {
      #pragma unroll
      for (int j = 0; j < 8; ++j) {
        const float v = p[8 * i + j];
        r[j] = __fadd_rn(r[j], __fmul_rn(v, v));
      }
    }
    e2f[k] = __fadd_rn(__fadd_rn(__fadd_rn(r[0], r[1]), __fadd_rn(r[2], r[3])),
                       __fadd_rn(__fadd_rn(r[4], r[5]), __fadd_rn(r[6], r[7])));
  }
}

// Phase 1: two-sweep hi-plane bf16 MFMA scoring. 64 rows/block (1024 blocks),
// 4 waves; each wave owns all 64 rows and a 16-col slice of each chunk.
// A fragments are loaded via VOLATILE dword reads: exactly-once semantics
// forbid the compiler's LDS-rematerialization (round-6 pathology: VGPR=76,
// afr re-read from zh every iter -> LDS-pipe-bound at 87us). With afr truly
// in VGPRs (~150 total, cap 170 at launch_bounds(256,3)) the loop has NO LDS
// traffic. Sweep loops unrolled x2 with named bA/bB double-buffer registers
// (no per-iter register copies). B loads: coalesced 1KB dwordx4 from SOA cbh.
// Sweep A: per-lane min -> shfl over 16 cols -> LDS reduce over 4 waves ->
// exact row-global min m. Sweep B: bitwise-identical recompute, append codes
// with s < m + marg_row (marg_row = 8.7e-5*sqrt(Arow)+1e-4). Cap 16;
// candcnt>16 or 0 -> exact fallback (expected: none).
__global__ __launch_bounds__(256, 3)
void score_kernel(const float* __restrict__ z, const ushort* __restrict__ cbh,
                  const float* __restrict__ e2f, float* __restrict__ Arow,
                  ushort* __restrict__ cand_g, int* __restrict__ candcnt) {
  __shared__ __attribute__((aligned(16))) ushort zh[8192]; // 16KB z hi plane (64x128)
  __shared__ float margL[64];
  __shared__ float sredA[256];       // [row][wv]
  __shared__ float thrF[64];
  __shared__ int cntL[64];
  __shared__ ushort candL[64 * 16];  // 2KB

  const int tid = threadIdx.x;
  const int n0 = blockIdx.x * 64;                // 1024 blocks
  const int b = n0 >> 10, t0 = n0 & 1023;
  const float* zb = z + (size_t)b * DT + t0;
  const int lane = tid & 63, wv = tid >> 6;
  const int col = lane & 15, quad = lane >> 4;

  // ---- prologue: stage z hi plane (64 rows x 128 d, 16B-granule swizzled) ----
  {
    const int i = tid & 63;           // row in block
    const int half = tid >> 6;        // 0..3
    #pragma unroll
    for (int g4 = 0; g4 < 4; ++g4) {
      const int gran = half * 4 + g4;
      short8 w;
      #pragma unroll
      for (int j = 0; j < 8; ++j) {
        const int d = gran * 8 + j;
        const float v = zb[d * Tt + i];            // coalesced over i
        const unsigned u = __float_as_uint(v);
        const unsigned hb = (u + 0x7FFFu + ((u >> 16) & 1u)) & 0xFFFF0000u;
        w[j] = (short)(hb >> 16);
      }
      *(short8*)&zh[i * 128 + ((gran ^ (i & 15)) << 3)] = w;
    }
  }
  // ---- Arow: np-pairwise fp32 ||x||^2 (bitwise = reference pass; z L1-hot) ----
  if (tid < 64) {
    const float* p = zb + tid;                    // x_d = p[d*Tt]
    float r[8];
    #pragma unroll
    for (int j = 0; j < 8; ++j) {
      const float v = p[j * Tt];
      r[j] = __fmul_rn(v, v);
    }
    for (int i = 1; i < 16; ++i) {
      #pragma unroll
      for (int j = 0; j < 8; ++j) {
        const float v = p[(8 * i + j) * Tt];
        r[j] = __fadd_rn(r[j], __fmul_rn(v, v));
      }
    }
    const float A = __fadd_rn(__fadd_rn(__fadd_rn(r[0], r[1]), __fadd_rn(r[2], r[3])),
                              __fadd_rn(__fadd_rn(r[4], r[5]), __fadd_rn(r[6], r[7])));
    Arow[n0 + tid] = A;
    margL[tid] = 8.7e-5f * sqrtf(A) + 1.0e-4f;
    cntL[tid] = 0;
  }
  __syncthreads();

  // ---- A fragments into registers (volatile: remat from LDS is illegal) ----
  short8 afr[4][4];
  #pragma unroll
  for (int rt = 0; rt < 4; ++rt)
    #pragma unroll
    for (int ks = 0; ks < 4; ++ks) {
      const int rw = rt * 16 + col;               // rw&15 == col
      const volatile unsigned* vp =
          (const volatile unsigned*)&zh[rw * 128 + (((ks * 4 + quad) ^ col) << 3)];
      union { unsigned u[4]; short8 s; } tmp;
      tmp.u[0] = vp[0]; tmp.u[1] = vp[1]; tmp.u[2] = vp[2]; tmp.u[3] = vp[3];
      afr[rt][ks] = tmp.s;
    }

  // per-lane B base in SOA layout: wave slice + lane*16B; frag ks at +1024B;
  // chunk stride 16384B (=8192 ushorts)
  const ushort* const bp0 = cbh + wv * 2048 + lane * 8;   // ushort units
  const float* const ep0 = e2f + wv * 16 + col;

  const float4v vzero = {0.f, 0.f, 0.f, 0.f};
  float rmin[16];
  #pragma unroll
  for (int sl = 0; sl < 16; ++sl) rmin[sl] = 1e30f;

  // ---- Sweep A: exact row-global min (barrier-free, unroll-2 dbuf) ----
  {
    short8 bA[4], bB[4];
    float eA, eB;
    #pragma unroll
    for (int ks = 0; ks < 4; ++ks) bA[ks] = *(const short8*)(bp0 + ks * 512);
    eA = ep0[0];
    for (int it = 0; it < 32; it += 2) {
      const ushort* p1 = bp0 + (size_t)(it + 1) * 8192;   // prefetch it+1 -> B
      #pragma unroll
      for (int ks = 0; ks < 4; ++ks) bB[ks] = *(const short8*)(p1 + ks * 512);
      eB = ep0[(it + 1) * 64];
      {
        float4v acc[4];
        #pragma unroll
        for (int rt = 0; rt < 4; ++rt) acc[rt] = vzero;
        #pragma unroll
        for (int ks = 0; ks < 4; ++ks)
          #pragma unroll
          for (int rt = 0; rt < 4; ++rt)
            acc[rt] = __builtin_amdgcn_mfma_f32_16x16x32_bf16(afr[rt][ks], bA[ks], acc[rt], 0, 0, 0);
        #pragma unroll
        for (int rt = 0; rt < 4; ++rt)
          #pragma unroll
          for (int r = 0; r < 4; ++r) {
            const float s = fmaf(-2.0f, acc[rt][r], eA);
            rmin[rt * 4 + r] = fminf(rmin[rt * 4 + r], s);
          }
      }
      const int c2 = (it + 2 < 32) ? (it + 2) : 31;       // prefetch it+2 -> A
      const ushort* p2 = bp0 + (size_t)c2 * 8192;
      #pragma unroll
      for (int ks = 0; ks < 4; ++ks) bA[ks] = *(const short8*)(p2 + ks * 512);
      eA = ep0[c2 * 64];
      {
        float4v acc[4];
        #pragma unroll
        for (int rt = 0; rt < 4; ++rt) acc[rt] = vzero;
        #pragma unroll
        for (int ks = 0; ks < 4; ++ks)
          #pragma unroll
          for (int rt = 0; rt < 4; ++rt)
            acc[rt] = __builtin_amdgcn_mfma_f32_16x16x32_bf16(afr[rt][ks], bB[ks], acc[rt], 0, 0, 0);
        #pragma unroll
        for (int rt = 0; rt < 4; ++rt)
          #pragma unroll
          for (int r = 0; r < 4; ++r) {
            const float s = fmaf(-2.0f, acc[rt][r], eB);
            rmin[rt * 4 + r] = fminf(rmin[rt * 4 + r], s);
          }
      }
    }
  }

  // ---- exact row-global min reduce: 16 cols (shfl) x 4 waves (LDS) ----
  #pragma unroll
  for (int sl = 0; sl < 16; ++sl) {
    float v = rmin[sl];
    v = fminf(v, __shfl_xor(v, 1, 64));
    v = fminf(v, __shfl_xor(v, 2, 64));
    v = fminf(v, __shfl_xor(v, 4, 64));
    v = fminf(v, __shfl_xor(v, 8, 64));
    rmin[sl] = v;
  }
  if (col == 0) {
    #pragma unroll
    for (int sl = 0; sl < 16; ++sl) {
      const int rw = (sl >> 2) * 16 + quad * 4 + (sl & 3);
      sredA[rw * 4 + wv] = rmin[sl];
    }
  }
  __syncthreads();
  if (tid < 64) {
    const float m = fminf(fminf(sredA[tid * 4], sredA[tid * 4 + 1]),
                          fminf(sredA[tid * 4 + 2], sredA[tid * 4 + 3]));
    thrF[tid] = m + margL[tid];
  }
  __syncthreads();
  #pragma unroll
  for (int sl = 0; sl < 16; ++sl)       // reuse rmin regs as per-slot thresholds
    rmin[sl] = thrF[(sl >> 2) * 16 + quad * 4 + (sl & 3)];

  // ---- Sweep B: bitwise-identical recompute, exact-threshold append ----
  {
    short8 bA[4], bB[4];
    float eA, eB;
    #pragma unroll
    for (int ks = 0; ks < 4; ++ks) bA[ks] = *(const short8*)(bp0 + ks * 512);
    eA = ep0[0];
    for (int it = 0; it < 32; it += 2) {
      const ushort* p1 = bp0 + (size_t)(it + 1) * 8192;
      #pragma unroll
      for (int ks = 0; ks < 4; ++ks) bB[ks] = *(const short8*)(p1 + ks * 512);
      eB = ep0[(it + 1) * 64];
      {
        float4v acc[4];
        #pragma unroll
        for (int rt = 0; rt < 4; ++rt) acc[rt] = vzero;
        #pragma unroll
        for (int ks = 0; ks < 4; ++ks)
          #pragma unroll
          for (int rt = 0; rt < 4; ++rt)
            acc[rt] = __builtin_amdgcn_mfma_f32_16x16x32_bf16(afr[rt][ks], bA[ks], acc[rt], 0, 0, 0);
        const int cbase = it * 64 + wv * 16 + col;
        #pragma unroll
        for (int rt = 0; rt < 4; ++rt)
          #pragma unroll
          for (int r = 0; r < 4; ++r) {
            const float s = fmaf(-2.0f, acc[rt][r], eA);
            if (s < rmin[rt * 4 + r]) {
              const int rw = rt * 16 + quad * 4 + r;
              const int pos = atomicAdd(&cntL[rw], 1);
              if (pos < 16) candL[rw * 16 + pos] = (ushort)cbase;
            }
          }
      }
      const int c2 = (it + 2 < 32) ? (it + 2) : 31;
      const ushort* p2 = bp0 + (size_t)c2 * 8192;
      #pragma unroll
      for (int ks = 0; ks < 4; ++ks) bA[ks] = *(const short8*)(p2 + ks * 512);
      eA = ep0[c2 * 64];
      {
        float4v acc[4];
        #pragma unroll
        for (int rt = 0; rt < 4; ++rt) acc[rt] = vzero;
        #pragma unroll
        for (int ks = 0; ks < 4; ++ks)
          #pragma unroll
          for (int rt = 0; rt < 4; ++rt)
            acc[rt] = __builtin_amdgcn_mfma_f32_16x16x32_bf16(afr[rt][ks], bB[ks], acc[rt], 0, 0, 0);
        const int cbase = (it + 1) * 64 + wv * 16 + col;
        #pragma unroll
        for (int rt = 0; rt < 4; ++rt)
          #pragma unroll
          for (int r = 0; r < 4; ++r) {
            const float s = fmaf(-2.0f, acc[rt][r], eB);
            if (s < rmin[rt * 4 + r]) {
              const int rw = rt * 16 + quad * 4 + r;
              const int pos = atomicAdd(&cntL[rw], 1);
              if (pos < 16) candL[rw * 16 + pos] = (ushort)cbase;
            }
          }
      }
    }
  }
  __syncthreads();
  if (tid < 64) {
    const int n = n0 + tid;
    candcnt[n] = cntL[tid];
    uint4* dst = (uint4*)(cand_g + (size_t)n * 16);
    const uint4* src = (const uint4*)(candL + tid * 16);
    dst[0] = src[0];
    dst[1] = src[1];
  }
}

// Phase 2: exact np-replica rescore + f64 commitment-loss partial via
// loss_row = A - 2*dot_win + e2[win] (f64; dot already computed for winner).
__global__ __launch_bounds__(256)
void rescore_kernel(const float* __restrict__ z, const float* __restrict__ cb,
                    const float* __restrict__ e2f, const float* __restrict__ Arow,
                    const ushort* __restrict__ cand_g, const int* __restrict__ candcnt,
                    int* __restrict__ idxbuf, int* __restrict__ counts,
                    float* __restrict__ out_idx, double* __restrict__ part) {
  const int tid = threadIdx.x;
  const int n = blockIdx.x * 256 + tid;           // 256 blocks
  const int c = candcnt[n];
  double sq = 0.0;
  if (c >= 1 && c <= 16) {                        // fallback handles the rest
    const int b = n >> 10, t = n & 1023;
    const float* zb = z + (size_t)b * DT + t;
    const float A = Arow[n];
    float best = 1e30f;
    int bk = Kk;
    double bacc = 0.0;
    for (int j = 0; j < c; ++j) {
      const int k = cand_g[(size_t)n * 16 + j];
      const float* e = cb + (size_t)k * Dd;
      double acc = 0.0;
      #pragma unroll 8
      for (int d = 0; d < 128; d += 4) {
        const float4 ev = *(const float4*)(e + d);
        acc += (double)zb[(d + 0) * Tt] * (double)ev.x;
        acc += (double)zb[(d + 1) * Tt] * (double)ev.y;
        acc += (double)zb[(d + 2) * Tt] * (double)ev.z;
        acc += (double)zb[(d + 3) * Tt] * (double)ev.w;
      }
      const float m32 = (float)acc;
      const float X = __fsub_rn(A, __fmul_rn(2.0f, m32));
      const float Dq = __fadd_rn(X, e2f[k]);
      if (Dq < best || (Dq == best && k < bk)) { best = Dq; bk = k; bacc = acc; }
    }
    idxbuf[n] = bk;
    out_idx[n] = (float)bk;
    atomicAdd(&counts[bk], 1);
    sq = (double)A - 2.0 * bacc + (double)e2f[bk];
  }
  #pragma unroll
  for (int o = 32; o > 0; o >>= 1) sq += __shfl_down(sq, o, 64);
  __shared__ double w4[4];
  if ((tid & 63) == 0) w4[tid >> 6] = sq;
  __syncthreads();
  if (tid == 0) part[blockIdx.x] = w4[0] + w4[1] + w4[2] + w4[3];
}

// Fallback: full exact scan for rows with empty/overflowed lists (expected:
// none). Contributes those rows' loss into part[256..511].
__global__ __launch_bounds__(256)
void fallback_kernel(const float* __restrict__ z, const float* __restrict__ cb,
                     const float* __restrict__ e2f, const float* __restrict__ Arow,
                     const int* __restrict__ candcnt, int* __restrict__ idxbuf,
                     int* __restrict__ counts, float* __restrict__ out_idx,
                     double* __restrict__ part) {
  __shared__ int flags[256];
  __shared__ int nf;
  __shared__ float xrow[128];
  __shared__ float rs[256];
  __shared__ int rk[256];
  const int tid = threadIdx.x;
  const int nb = blockIdx.x * 256;                // 256 blocks
  if (tid == 0) { nf = 0; part[256 + blockIdx.x] = 0.0; }
  __syncthreads();
  const int c = candcnt[nb + tid];
  const int bad = (c < 1 || c > 16) ? 1 : 0;
  flags[tid] = bad;
  if (bad) atomicAdd(&nf, 1);
  __syncthreads();
  if (nf == 0) return;                            // fast path
  double bsum = 0.0;
  for (int rr = 0; rr < 256; ++rr) {
    if (!flags[rr]) continue;                     // block-uniform
    const int n = nb + rr;
    const int b = n >> 10, t = n & 1023;
    if (tid < 128) xrow[tid] = z[(size_t)b * DT + (size_t)tid * Tt + t];
    __syncthreads();
    const float A = Arow[n];
    float best = 1e30f;
    int bk = Kk;
    for (int kk = tid * 8; kk < tid * 8 + 8; ++kk) {
      const float* e = cb + (size_t)kk * Dd;
      double acc = 0.0;
      for (int d = 0; d < 128; d += 4) {
        const float4 ev = *(const float4*)(e + d);
        acc += (double)xrow[d + 0] * (double)ev.x;
        acc += (double)xrow[d + 1] * (double)ev.y;
        acc += (double)xrow[d + 2] * (double)ev.z;
        acc += (double)xrow[d + 3] * (double)ev.w;
      }
      const float m32 = (float)acc;
      const float Dq = __fadd_rn(__fsub_rn(A, __fmul_rn(2.0f, m32)), e2f[kk]);
      if (Dq < best || (Dq == best && kk < bk)) { best = Dq; bk = kk; }
    }
    rs[tid] = best;
    rk[tid] = bk;
    __syncthreads();
    for (int o = 128; o > 0; o >>= 1) {
      if (tid < o) {
        if (rs[tid + o] < rs[tid] || (rs[tid + o] == rs[tid] && rk[tid + o] < rk[tid])) {
          rs[tid] = rs[tid + o];
          rk[tid] = rk[tid + o];
        }
      }
      __syncthreads();
    }
    if (tid == 0) {
      const int w = rk[0];
      idxbuf[n] = w;
      out_idx[n] = (float)w;
      atomicAdd(&counts[w], 1);
      const float* ew = cb + (size_t)w * Dd;
      for (int d = 0; d < 128; ++d) {
        const double dif = (double)xrow[d] - (double)ew[d];
        bsum += dif * dif;
      }
    }
    __syncthreads();
  }
  if (tid == 0) part[256 + blockIdx.x] = bsum;
}

// Gather z_q into (B,D,T) layout, LDS-transpose version: stage 64 code-rows
// (16B-granule gathers, 4x fewer L1 transactions than per-element) into
// padded LDS, then write coalesced 256B runs per d-row.
__global__ __launch_bounds__(256)
void gather_kernel(const float* __restrict__ cb, const int* __restrict__ idxbuf,
                   float* __restrict__ out0) {
  __shared__ float ef[64 * 132];     // 33.8KB, stride 132 floats (16B-aligned)
  __shared__ int sidx[64];
  const int tid = threadIdx.x;
  const int n0 = blockIdx.x * 64;    // 1024 blocks; 64 consecutive t, same b
  const int b = n0 >> 10, t0 = n0 & 1023;
  if (tid < 64) sidx[tid] = idxbuf[n0 + tid];
  __syncthreads();
  {
    const int r = tid & 63, q = tid >> 6;         // wave q stages chunk q
    const float* src = cb + (size_t)sidx[r] * Dd + q * 32;
    float* dst = ef + r * 132 + q * 32;
    #pragma unroll
    for (int j = 0; j < 8; ++j)
      *(float4*)(dst + 4 * j) = *(const float4*)(src + 4 * j);
  }
  __syncthreads();
  {
    const int l = tid & 63, w = tid >> 6;         // wave w writes d = w*32..w*32+31
    float* ob = out0 + ((size_t)b << 17) + (size_t)(w * 32) * 1024 + t0 + l;
    #pragma unroll
    for (int i = 0; i < 32; ++i)
      ob[(size_t)i * 1024] = ef[l * 132 + w * 32 + i];
  }
}

__global__ __launch_bounds__(256)
void finalize_kernel(const int* __restrict__ counts, const double* __restrict__ part,
                     float* __restrict__ out) {
  const int tid = threadIdx.x;
  __shared__ double red[256];
  double s = 0.0;
  for (int i = tid; i < 512; i += 256) s += part[i];
  red[tid] = s;
  __syncthreads();
  for (int o = 128; o > 0; o >>= 1) {
    if (tid < o) red[tid] += red[tid + o];
    __syncthreads();
  }
  const double loss = red[0];
  __syncthreads();
  double e = 0.0;
  for (int k = tid; k < 2048; k += 256) {
    const double p = (double)counts[k] / 65536.0;
    e += p * log(p + 1e-10);
  }
  red[tid] = e;
  __syncthreads();
  for (int o = 128; o > 0; o >>= 1) {
    if (tid < o) red[tid] += red[tid + o];
    __syncthreads();
  }
  if (tid == 0) {
    out[8388608] = (float)(0.25 * loss / 8388608.0);
    out[8388609] = (float)exp(-red[0]);
  }
}

extern "C" void kernel_launch(void* const* d_in, const int* in_sizes, int n_in,
                              void* d_out, int out_size, void* d_ws, size_t ws_size,
                              hipStream_t stream) {
  const float* z = (const float*)d_in[0];      // (B, D, T) fp32
  const float* cb = (const float*)d_in[1];     // (K, D) fp32
  float* out = (float*)d_out;                  // [z_q (8388608) | loss | perp | idx (65536)]
  char* ws = (char*)d_ws;
  ushort* cbh    = (ushort*)ws;
  float* e2f     = (float*)(ws + 524288);
  float* Arow    = (float*)(ws + 532480);
  int* idxbuf    = (int*)(ws + 794624);
  int* counts    = (int*)(ws + 1056768);
  double* part   = (double*)(ws + 1064960);
  ushort* cand_g = (ushort*)(ws + 1069056);
  int* candcnt   = (int*)(ws + 3166208);

  hipLaunchKernelGGL(setup_kernel,    dim3(136),  dim3(256), 0, stream, cb, cbh, e2f, counts);
  hipLaunchKernelGGL(score_kernel,    dim3(1024), dim3(256), 0, stream, z, cbh, e2f, Arow,
                     cand_g, candcnt);
  hipLaunchKernelGGL(rescore_kernel,  dim3(256),  dim3(256), 0, stream, z, cb, e2f, Arow,
                     cand_g, candcnt, idxbuf, counts, out + 8388610, part);
  hipLaunchKernelGGL(fallback_kernel, dim3(256),  dim3(256), 0, stream, z, cb, e2f, Arow,
                     candcnt, idxbuf, counts, out + 8388610, part);
  hipLaunchKernelGGL(gather_kernel,   dim3(1024), dim3(256), 0, stream, cb, idxbuf, out);
  hipLaunchKernelGGL(finalize_kernel, dim3(1),    dim3(256), 0, stream, counts, part, out);
}

// Round 8
// 230.192 us; speedup vs baseline: 2.7440x; 1.0023x over previous
//
#include <hip/hip_runtime.h>
#include <math.h>

#define Dd 128
#define Tt 1024
#define Kk 2048
#define Nn 65536
#define DT 131072  // Dd*Tt

typedef __attribute__((ext_vector_type(8))) short short8;
typedef __attribute__((ext_vector_type(4))) float float4v;

// ws layout (bytes):
//   cbh     @ 0        : ushort[262144] = 524288   (bf16 hi plane of codebook, SOA-fragment layout)
//   e2f     @ 524288   : float[2048]    = 8192     (np-replica fp32 ||e||^2)
//   Arow    @ 532480   : float[65536]   = 262144   (np-replica fp32 ||x||^2, written by score_kernel)
//   idxbuf  @ 794624   : int[65536]     = 262144
//   counts  @ 1056768  : int[2048]      = 8192
//   part    @ 1064960  : double[512]    = 4096
//   cand_g  @ 1069056  : ushort[65536*16] = 2097152
//   candcnt @ 3166208  : int[65536]     = 262144
// total 3428352 B (~3.43 MB)
//
// cbh SOA layout: for code k, 16B granule g (g of the 256B row):
//   chunk=k>>6, wv=(k>>4)&3, col=k&15, ks=g>>2, quad=g&3
//   byte dest = chunk*16384 + wv*4096 + ks*1024 + quad*256 + col*16
// => score_kernel per-(wave,iter,ks) B-fragment load is lane*16B contiguous (1 KB).

// Setup: SOA bf16-hi split of codebook (blocks 0..127) + np-replica fp32
// ||e||^2 / counts-zero (blocks 128..135).
__global__ __launch_bounds__(256)
void setup_kernel(const float* __restrict__ cb, ushort* __restrict__ cbh,
                  float* __restrict__ e2f, int* __restrict__ counts) {
  const int bid = blockIdx.x, tid = threadIdx.x;
  if (bid < 128) {
    const int gi = bid * 256 + tid;               // 32768 granules (16B each)
    const int k = gi >> 4, g = gi & 15;
    const float* p = cb + (size_t)k * Dd + g * 8; // 32B coalesced read
    short8 w;
    #pragma unroll
    for (int j = 0; j < 8; ++j) {
      const unsigned u = __float_as_uint(p[j]);
      const unsigned hb = (u + 0x7FFFu + ((u >> 16) & 1u)) & 0xFFFF0000u;  // RNE bf16
      w[j] = (short)(hb >> 16);
    }
    const int chunk = k >> 6, wvv = (k >> 4) & 3, colc = k & 15;
    *(short8*)((char*)cbh + chunk * 16384 + wvv * 4096 + (g >> 2) * 1024 +
               (g & 3) * 256 + colc * 16) = w;
  } else {
    const int k = (bid - 128) * 256 + tid;        // 2048 codes
    counts[k] = 0;
    const float* p = cb + (size_t)k * Dd;
    float r[8];
    #pragma unroll
    for (int j = 0; j < 8; ++j) r[j] = __fmul_rn(p[j], p[j]);
    for (int i = 1; i < 16; ++i) {
      #pragma unroll
      for (int j = 0; j < 8; ++j) {
        const float v = p[8 * i + j];
        r[j] = __fadd_rn(r[j], __fmul_rn(v, v));
      }
    }
    e2f[k] = __fadd_rn(__fadd_rn(__fadd_rn(r[0], r[1]), __fadd_rn(r[2], r[3])),
                       __fadd_rn(__fadd_rn(r[4], r[5]), __fadd_rn(r[6], r[7])));
  }
}

// Phase 1: two-sweep hi-plane bf16 MFMA scoring. 64 rows/block (1024 blocks),
// 4 waves; each wave owns all 64 rows and a 16-col slice of each chunk.
// A fragments: plain ds_read_b128 into a flat static-indexed array, then an
// OPAQUE "+v" asm pin. Post-pin the values are not load-results anymore ->
// the allocator cannot rematerialize from LDS (round-6 pathology) and must
// keep them resident (~145 VGPR total, cap 170 at launch_bounds(256,3)).
// The main loops then have ZERO LDS traffic; B = coalesced 1KB dwordx4 from
// SOA cbh with unroll-2 named double-buffer (no per-iter register copies).
// Sweep A: per-lane min -> shfl over 16 cols -> LDS reduce over 4 waves ->
// exact row-global min m. Sweep B: bitwise-identical recompute, append codes
// with s < m + marg_row (marg_row = 8.7e-5*sqrt(Arow)+1e-4). Cap 16;
// candcnt>16 or 0 -> exact fallback (expected: none).
__global__ __launch_bounds__(256, 3)
void score_kernel(const float* __restrict__ z, const ushort* __restrict__ cbh,
                  const float* __restrict__ e2f, float* __restrict__ Arow,
                  ushort* __restrict__ cand_g, int* __restrict__ candcnt) {
  __shared__ __attribute__((aligned(16))) ushort zh[8192]; // 16KB z hi plane (64x128)
  __shared__ float margL[64];
  __shared__ float sredA[256];       // [row][wv]
  __shared__ float thrF[64];
  __shared__ int cntL[64];
  __shared__ ushort candL[64 * 16];  // 2KB

  const int tid = threadIdx.x;
  const int n0 = blockIdx.x * 64;                // 1024 blocks
  const int b = n0 >> 10, t0 = n0 & 1023;
  const float* zb = z + (size_t)b * DT + t0;
  const int lane = tid & 63, wv = tid >> 6;
  const int col = lane & 15, quad = lane >> 4;

  // ---- prologue: stage z hi plane (64 rows x 128 d, 16B-granule swizzled) ----
  {
    const int i = tid & 63;           // row in block
    const int half = tid >> 6;        // 0..3
    #pragma unroll
    for (int g4 = 0; g4 < 4; ++g4) {
      const int gran = half * 4 + g4;
      short8 w;
      #pragma unroll
      for (int j = 0; j < 8; ++j) {
        const int d = gran * 8 + j;
        const float v = zb[d * Tt + i];            // coalesced over i
        const unsigned u = __float_as_uint(v);
        const unsigned hb = (u + 0x7FFFu + ((u >> 16) & 1u)) & 0xFFFF0000u;
        w[j] = (short)(hb >> 16);
      }
      *(short8*)&zh[i * 128 + ((gran ^ (i & 15)) << 3)] = w;
    }
  }
  // ---- Arow: np-pairwise fp32 ||x||^2 (bitwise = reference pass; z L1-hot) ----
  if (tid < 64) {
    const float* p = zb + tid;                    // x_d = p[d*Tt]
    float r[8];
    #pragma unroll
    for (int j = 0; j < 8; ++j) {
      const float v = p[j * Tt];
      r[j] = __fmul_rn(v, v);
    }
    for (int i = 1; i < 16; ++i) {
      #pragma unroll
      for (int j = 0; j < 8; ++j) {
        const float v = p[(8 * i + j) * Tt];
        r[j] = __fadd_rn(r[j], __fmul_rn(v, v));
      }
    }
    const float A = __fadd_rn(__fadd_rn(__fadd_rn(r[0], r[1]), __fadd_rn(r[2], r[3])),
                              __fadd_rn(__fadd_rn(r[4], r[5]), __fadd_rn(r[6], r[7])));
    Arow[n0 + tid] = A;
    margL[tid] = 8.7e-5f * sqrtf(A) + 1.0e-4f;
    cntL[tid] = 0;
  }
  __syncthreads();

  // ---- A fragments: plain b128 reads, then opaque pin (no remat possible) ----
  short8 afr[16];
  #pragma unroll
  for (int rt = 0; rt < 4; ++rt)
    #pragma unroll
    for (int ks = 0; ks < 4; ++ks) {
      const int rw = rt * 16 + col;               // rw&15 == col
      afr[rt * 4 + ks] = *(const short8*)&zh[rw * 128 + (((ks * 4 + quad) ^ col) << 3)];
    }
  asm volatile("" : "+v"(afr[0]), "+v"(afr[1]), "+v"(afr[2]), "+v"(afr[3]),
                    "+v"(afr[4]), "+v"(afr[5]), "+v"(afr[6]), "+v"(afr[7]),
                    "+v"(afr[8]), "+v"(afr[9]), "+v"(afr[10]), "+v"(afr[11]),
                    "+v"(afr[12]), "+v"(afr[13]), "+v"(afr[14]), "+v"(afr[15]));

  // per-lane B base in SOA layout: wave slice + lane*16B; frag ks at +1024B;
  // chunk stride 16384B (=8192 ushorts)
  const ushort* const bp0 = cbh + wv * 2048 + lane * 8;   // ushort units
  const float* const ep0 = e2f + wv * 16 + col;

  const float4v vzero = {0.f, 0.f, 0.f, 0.f};
  float rmin[16];
  #pragma unroll
  for (int sl = 0; sl < 16; ++sl) rmin[sl] = 1e30f;

  // ---- Sweep A: exact row-global min (barrier-free, unroll-2 dbuf) ----
  {
    short8 bA[4], bB[4];
    float eA, eB;
    #pragma unroll
    for (int ks = 0; ks < 4; ++ks) bA[ks] = *(const short8*)(bp0 + ks * 512);
    eA = ep0[0];
    for (int it = 0; it < 32; it += 2) {
      const ushort* p1 = bp0 + (size_t)(it + 1) * 8192;   // prefetch it+1 -> B
      #pragma unroll
      for (int ks = 0; ks < 4; ++ks) bB[ks] = *(const short8*)(p1 + ks * 512);
      eB = ep0[(it + 1) * 64];
      {
        float4v acc[4];
        #pragma unroll
        for (int rt = 0; rt < 4; ++rt) acc[rt] = vzero;
        #pragma unroll
        for (int ks = 0; ks < 4; ++ks)
          #pragma unroll
          for (int rt = 0; rt < 4; ++rt)
            acc[rt] = __builtin_amdgcn_mfma_f32_16x16x32_bf16(afr[rt * 4 + ks], bA[ks], acc[rt], 0, 0, 0);
        #pragma unroll
        for (int rt = 0; rt < 4; ++rt)
          #pragma unroll
          for (int r = 0; r < 4; ++r) {
            const float s = fmaf(-2.0f, acc[rt][r], eA);
            rmin[rt * 4 + r] = fminf(rmin[rt * 4 + r], s);
          }
      }
      const int c2 = (it + 2 < 32) ? (it + 2) : 31;       // prefetch it+2 -> A
      const ushort* p2 = bp0 + (size_t)c2 * 8192;
      #pragma unroll
      for (int ks = 0; ks < 4; ++ks) bA[ks] = *(const short8*)(p2 + ks * 512);
      eA = ep0[c2 * 64];
      {
        float4v acc[4];
        #pragma unroll
        for (int rt = 0; rt < 4; ++rt) acc[rt] = vzero;
        #pragma unroll
        for (int ks = 0; ks < 4; ++ks)
          #pragma unroll
          for (int rt = 0; rt < 4; ++rt)
            acc[rt] = __builtin_amdgcn_mfma_f32_16x16x32_bf16(afr[rt * 4 + ks], bB[ks], acc[rt], 0, 0, 0);
        #pragma unroll
        for (int rt = 0; rt < 4; ++rt)
          #pragma unroll
          for (int r = 0; r < 4; ++r) {
            const float s = fmaf(-2.0f, acc[rt][r], eB);
            rmin[rt * 4 + r] = fminf(rmin[rt * 4 + r], s);
          }
      }
    }
  }

  // ---- exact row-global min reduce: 16 cols (shfl) x 4 waves (LDS) ----
  #pragma unroll
  for (int sl = 0; sl < 16; ++sl) {
    float v = rmin[sl];
    v = fminf(v, __shfl_xor(v, 1, 64));
    v = fminf(v, __shfl_xor(v, 2, 64));
    v = fminf(v, __shfl_xor(v, 4, 64));
    v = fminf(v, __shfl_xor(v, 8, 64));
    rmin[sl] = v;
  }
  if (col == 0) {
    #pragma unroll
    for (int sl = 0; sl < 16; ++sl) {
      const int rw = (sl >> 2) * 16 + quad * 4 + (sl & 3);
      sredA[rw * 4 + wv] = rmin[sl];
    }
  }
  __syncthreads();
  if (tid < 64) {
    const float m = fminf(fminf(sredA[tid * 4], sredA[tid * 4 + 1]),
                          fminf(sredA[tid * 4 + 2], sredA[tid * 4 + 3]));
    thrF[tid] = m + margL[tid];
  }
  __syncthreads();
  #pragma unroll
  for (int sl = 0; sl < 16; ++sl)       // reuse rmin regs as per-slot thresholds
    rmin[sl] = thrF[(sl >> 2) * 16 + quad * 4 + (sl & 3)];

  // ---- Sweep B: bitwise-identical recompute, exact-threshold append ----
  {
    short8 bA[4], bB[4];
    float eA, eB;
    #pragma unroll
    for (int ks = 0; ks < 4; ++ks) bA[ks] = *(const short8*)(bp0 + ks * 512);
    eA = ep0[0];
    for (int it = 0; it < 32; it += 2) {
      const ushort* p1 = bp0 + (size_t)(it + 1) * 8192;
      #pragma unroll
      for (int ks = 0; ks < 4; ++ks) bB[ks] = *(const short8*)(p1 + ks * 512);
      eB = ep0[(it + 1) * 64];
      {
        float4v acc[4];
        #pragma unroll
        for (int rt = 0; rt < 4; ++rt) acc[rt] = vzero;
        #pragma unroll
        for (int ks = 0; ks < 4; ++ks)
          #pragma unroll
          for (int rt = 0; rt < 4; ++rt)
            acc[rt] = __builtin_amdgcn_mfma_f32_16x16x32_bf16(afr[rt * 4 + ks], bA[ks], acc[rt], 0, 0, 0);
        const int cbase = it * 64 + wv * 16 + col;
        #pragma unroll
        for (int rt = 0; rt < 4; ++rt)
          #pragma unroll
          for (int r = 0; r < 4; ++r) {
            const float s = fmaf(-2.0f, acc[rt][r], eA);
            if (s < rmin[rt * 4 + r]) {
              const int rw = rt * 16 + quad * 4 + r;
              const int pos = atomicAdd(&cntL[rw], 1);
              if (pos < 16) candL[rw * 16 + pos] = (ushort)cbase;
            }
          }
      }
      const int c2 = (it + 2 < 32) ? (it + 2) : 31;
      const ushort* p2 = bp0 + (size_t)c2 * 8192;
      #pragma unroll
      for (int ks = 0; ks < 4; ++ks) bA[ks] = *(const short8*)(p2 + ks * 512);
      eA = ep0[c2 * 64];
      {
        float4v acc[4];
        #pragma unroll
        for (int rt = 0; rt < 4; ++rt) acc[rt] = vzero;
        #pragma unroll
        for (int ks = 0; ks < 4; ++ks)
          #pragma unroll
          for (int rt = 0; rt < 4; ++rt)
            acc[rt] = __builtin_amdgcn_mfma_f32_16x16x32_bf16(afr[rt * 4 + ks], bB[ks], acc[rt], 0, 0, 0);
        const int cbase = (it + 1) * 64 + wv * 16 + col;
        #pragma unroll
        for (int rt = 0; rt < 4; ++rt)
          #pragma unroll
          for (int r = 0; r < 4; ++r) {
            const float s = fmaf(-2.0f, acc[rt][r], eB);
            if (s < rmin[rt * 4 + r]) {
              const int rw = rt * 16 + quad * 4 + r;
              const int pos = atomicAdd(&cntL[rw], 1);
              if (pos < 16) candL[rw * 16 + pos] = (ushort)cbase;
            }
          }
      }
    }
  }
  __syncthreads();
  if (tid < 64) {
    const int n = n0 + tid;
    candcnt[n] = cntL[tid];
    uint4* dst = (uint4*)(cand_g + (size_t)n * 16);
    const uint4* src = (const uint4*)(candL + tid * 16);
    dst[0] = src[0];
    dst[1] = src[1];
  }
}

// Phase 2: exact np-replica rescore + f64 commitment-loss partial via
// loss_row = A - 2*dot_win + e2[win] (f64; dot already computed for winner).
__global__ __launch_bounds__(256)
void rescore_kernel(const float* __restrict__ z, const float* __restrict__ cb,
                    const float* __restrict__ e2f, const float* __restrict__ Arow,
                    const ushort* __restrict__ cand_g, const int* __restrict__ candcnt,
                    int* __restrict__ idxbuf, int* __restrict__ counts,
                    float* __restrict__ out_idx, double* __restrict__ part) {
  const int tid = threadIdx.x;
  const int n = blockIdx.x * 256 + tid;           // 256 blocks
  const int c = candcnt[n];
  double sq = 0.0;
  if (c >= 1 && c <= 16) {                        // fallback handles the rest
    const int b = n >> 10, t = n & 1023;
    const float* zb = z + (size_t)b * DT + t;
    const float A = Arow[n];
    float best = 1e30f;
    int bk = Kk;
    double bacc = 0.0;
    for (int j = 0; j < c; ++j) {
      const int k = cand_g[(size_t)n * 16 + j];
      const float* e = cb + (size_t)k * Dd;
      double acc = 0.0;
      #pragma unroll 8
      for (int d = 0; d < 128; d += 4) {
        const float4 ev = *(const float4*)(e + d);
        acc += (double)zb[(d + 0) * Tt] * (double)ev.x;
        acc += (double)zb[(d + 1) * Tt] * (double)ev.y;
        acc += (double)zb[(d + 2) * Tt] * (double)ev.z;
        acc += (double)zb[(d + 3) * Tt] * (double)ev.w;
      }
      const float m32 = (float)acc;
      const float X = __fsub_rn(A, __fmul_rn(2.0f, m32));
      const float Dq = __fadd_rn(X, e2f[k]);
      if (Dq < best || (Dq == best && k < bk)) { best = Dq; bk = k; bacc = acc; }
    }
    idxbuf[n] = bk;
    out_idx[n] = (float)bk;
    atomicAdd(&counts[bk], 1);
    sq = (double)A - 2.0 * bacc + (double)e2f[bk];
  }
  #pragma unroll
  for (int o = 32; o > 0; o >>= 1) sq += __shfl_down(sq, o, 64);
  __shared__ double w4[4];
  if ((tid & 63) == 0) w4[tid >> 6] = sq;
  __syncthreads();
  if (tid == 0) part[blockIdx.x] = w4[0] + w4[1] + w4[2] + w4[3];
}

// Fallback: full exact scan for rows with empty/overflowed lists (expected:
// none). Contributes those rows' loss into part[256..511].
__global__ __launch_bounds__(256)
void fallback_kernel(const float* __restrict__ z, const float* __restrict__ cb,
                     const float* __restrict__ e2f, const float* __restrict__ Arow,
                     const int* __restrict__ candcnt, int* __restrict__ idxbuf,
                     int* __restrict__ counts, float* __restrict__ out_idx,
                     double* __restrict__ part) {
  __shared__ int flags[256];
  __shared__ int nf;
  __shared__ float xrow[128];
  __shared__ float rs[256];
  __shared__ int rk[256];
  const int tid = threadIdx.x;
  const int nb = blockIdx.x * 256;                // 256 blocks
  if (tid == 0) { nf = 0; part[256 + blockIdx.x] = 0.0; }
  __syncthreads();
  const int c = candcnt[nb + tid];
  const int bad = (c < 1 || c > 16) ? 1 : 0;
  flags[tid] = bad;
  if (bad) atomicAdd(&nf, 1);
  __syncthreads();
  if (nf == 0) return;                            // fast path
  double bsum = 0.0;
  for (int rr = 0; rr < 256; ++rr) {
    if (!flags[rr]) continue;                     // block-uniform
    const int n = nb + rr;
    const int b = n >> 10, t = n & 1023;
    if (tid < 128) xrow[tid] = z[(size_t)b * DT + (size_t)tid * Tt + t];
    __syncthreads();
    const float A = Arow[n];
    float best = 1e30f;
    int bk = Kk;
    for (int kk = tid * 8; kk < tid * 8 + 8; ++kk) {
      const float* e = cb + (size_t)kk * Dd;
      double acc = 0.0;
      for (int d = 0; d < 128; d += 4) {
        const float4 ev = *(const float4*)(e + d);
        acc += (double)xrow[d + 0] * (double)ev.x;
        acc += (double)xrow[d + 1] * (double)ev.y;
        acc += (double)xrow[d + 2] * (double)ev.z;
        acc += (double)xrow[d + 3] * (double)ev.w;
      }
      const float m32 = (float)acc;
      const float Dq = __fadd_rn(__fsub_rn(A, __fmul_rn(2.0f, m32)), e2f[kk]);
      if (Dq < best || (Dq == best && kk < bk)) { best = Dq; bk = kk; }
    }
    rs[tid] = best;
    rk[tid] = bk;
    __syncthreads();
    for (int o = 128; o > 0; o >>= 1) {
      if (tid < o) {
        if (rs[tid + o] < rs[tid] || (rs[tid + o] == rs[tid] && rk[tid + o] < rk[tid])) {
          rs[tid] = rs[tid + o];
          rk[tid] = rk[tid + o];
        }
      }
      __syncthreads();
    }
    if (tid == 0) {
      const int w = rk[0];
      idxbuf[n] = w;
      out_idx[n] = (float)w;
      atomicAdd(&counts[w], 1);
      const float* ew = cb + (size_t)w * Dd;
      for (int d = 0; d < 128; ++d) {
        const double dif = (double)xrow[d] - (double)ew[d];
        bsum += dif * dif;
      }
    }
    __syncthreads();
  }
  if (tid == 0) part[256 + blockIdx.x] = bsum;
}

// Gather z_q into (B,D,T) layout, LDS-transpose version: stage 64 code-rows
// (16B-granule gathers, 4x fewer L1 transactions than per-element) into
// padded LDS, then write coalesced 256B runs per d-row.
__global__ __launch_bounds__(256)
void gather_kernel(const float* __restrict__ cb, const int* __restrict__ idxbuf,
                   float* __restrict__ out0) {
  __shared__ float ef[64 * 132];     // 33.8KB, stride 132 floats (16B-aligned)
  __shared__ int sidx[64];
  const int tid = threadIdx.x;
  const int n0 = blockIdx.x * 64;    // 1024 blocks; 64 consecutive t, same b
  const int b = n0 >> 10, t0 = n0 & 1023;
  if (tid < 64) sidx[tid] = idxbuf[n0 + tid];
  __syncthreads();
  {
    const int r = tid & 63, q = tid >> 6;         // wave q stages chunk q
    const float* src = cb + (size_t)sidx[r] * Dd + q * 32;
    float* dst = ef + r * 132 + q * 32;
    #pragma unroll
    for (int j = 0; j < 8; ++j)
      *(float4*)(dst + 4 * j) = *(const float4*)(src + 4 * j);
  }
  __syncthreads();
  {
    const int l = tid & 63, w = tid >> 6;         // wave w writes d = w*32..w*32+31
    float* ob = out0 + ((size_t)b << 17) + (size_t)(w * 32) * 1024 + t0 + l;
    #pragma unroll
    for (int i = 0; i < 32; ++i)
      ob[(size_t)i * 1024] = ef[l * 132 + w * 32 + i];
  }
}

__global__ __launch_bounds__(256)
void finalize_kernel(const int* __restrict__ counts, const double* __restrict__ part,
                     float* __restrict__ out) {
  const int tid = threadIdx.x;
  __shared__ double red[256];
  double s = 0.0;
  for (int i = tid; i < 512; i += 256) s += part[i];
  red[tid] = s;
  __syncthreads();
  for (int o = 128; o > 0; o >>= 1) {
    if (tid < o) red[tid] += red[tid + o];
    __syncthreads();
  }
  const double loss = red[0];
  __syncthreads();
  double e = 0.0;
  for (int k = tid; k < 2048; k += 256) {
    const double p = (double)counts[k] / 65536.0;
    e += p * log(p + 1e-10);
  }
  red[tid] = e;
  __syncthreads();
  for (int o = 128; o > 0; o >>= 1) {
    if (tid < o) red[tid] += red[tid + o];
    __syncthreads();
  }
  if (tid == 0) {
    out[8388608] = (float)(0.25 * loss / 8388608.0);
    out[8388609] = (float)exp(-red[0]);
  }
}

extern "C" void kernel_launch(void* const* d_in, const int* in_sizes, int n_in,
                              void* d_out, int out_size, void* d_ws, size_t ws_size,
                              hipStream_t stream) {
  const float* z = (const float*)d_in[0];      // (B, D, T) fp32
  const float* cb = (const float*)d_in[1];     // (K, D) fp32
  float* out = (float*)d_out;                  // [z_q (8388608) | loss | perp | idx (65536)]
  char* ws = (char*)d_ws;
  ushort* cbh    = (ushort*)ws;
  float* e2f     = (float*)(ws + 524288);
  float* Arow    = (float*)(ws + 532480);
  int* idxbuf    = (int*)(ws + 794624);
  int* counts    = (int*)(ws + 1056768);
  double* part   = (double*)(ws + 1064960);
  ushort* cand_g = (ushort*)(ws + 1069056);
  int* candcnt   = (int*)(ws + 3166208);

  hipLaunchKernelGGL(setup_kernel,    dim3(136),  dim3(256), 0, stream, cb, cbh, e2f, counts);
  hipLaunchKernelGGL(score_kernel,    dim3(1024), dim3(256), 0, stream, z, cbh, e2f, Arow,
                     cand_g, candcnt);
  hipLaunchKernelGGL(rescore_kernel,  dim3(256),  dim3(256), 0, stream, z, cb, e2f, Arow,
                     cand_g, candcnt, idxbuf, counts, out + 8388610, part);
  hipLaunchKernelGGL(fallback_kernel, dim3(256),  dim3(256), 0, stream, z, cb, e2f, Arow,
                     candcnt, idxbuf, counts, out + 8388610, part);
  hipLaunchKernelGGL(gather_kernel,   dim3(1024), dim3(256), 0, stream, cb, idxbuf, out);
  hipLaunchKernelGGL(finalize_kernel, dim3(1),    dim3(256), 0, stream, counts, part, out);
}

// Round 9
// 227.807 us; speedup vs baseline: 2.7727x; 1.0105x over previous
//
#include <hip/hip_runtime.h>
#include <math.h>

#define Dd 128
#define Tt 1024
#define Kk 2048
#define Nn 65536
#define DT 131072  // Dd*Tt

typedef __attribute__((ext_vector_type(8))) short short8;
typedef __attribute__((ext_vector_type(4))) float float4v;

// ws layout (bytes):
//   cbh     @ 0        : ushort[262144] = 524288   (bf16 hi plane of codebook, SOA-fragment layout)
//   e2f     @ 524288   : float[2048]    = 8192     (np-replica fp32 ||e||^2)
//   Arow    @ 532480   : float[65536]   = 262144   (np-replica fp32 ||x||^2, written by score_kernel)
//   idxbuf  @ 794624   : int[65536]     = 262144
//   counts  @ 1056768  : int[2048]      = 8192
//   part    @ 1064960  : double[512]    = 4096
//   cand_g  @ 1069056  : ushort[65536*16] = 2097152
//   candcnt @ 3166208  : int[65536]     = 262144
// total 3428352 B (~3.43 MB)
//
// cbh SOA layout: for code k, 16B granule g (g of the 256B row):
//   chunk=k>>6, wv=(k>>4)&3, col=k&15, ks=g>>2, quad=g&3
//   byte dest = chunk*16384 + wv*4096 + ks*1024 + quad*256 + col*16
// => score_kernel per-(wave,iter,ks) B-fragment load is lane*16B contiguous (1 KB).

// Setup: SOA bf16-hi split of codebook (blocks 0..127) + np-replica fp32
// ||e||^2 / counts-zero (blocks 128..135).
__global__ __launch_bounds__(256)
void setup_kernel(const float* __restrict__ cb, ushort* __restrict__ cbh,
                  float* __restrict__ e2f, int* __restrict__ counts) {
  const int bid = blockIdx.x, tid = threadIdx.x;
  if (bid < 128) {
    const int gi = bid * 256 + tid;               // 32768 granules (16B each)
    const int k = gi >> 4, g = gi & 15;
    const float* p = cb + (size_t)k * Dd + g * 8; // 32B coalesced read
    short8 w;
    #pragma unroll
    for (int j = 0; j < 8; ++j) {
      const unsigned u = __float_as_uint(p[j]);
      const unsigned hb = (u + 0x7FFFu + ((u >> 16) & 1u)) & 0xFFFF0000u;  // RNE bf16
      w[j] = (short)(hb >> 16);
    }
    const int chunk = k >> 6, wvv = (k >> 4) & 3, colc = k & 15;
    *(short8*)((char*)cbh + chunk * 16384 + wvv * 4096 + (g >> 2) * 1024 +
               (g & 3) * 256 + colc * 16) = w;
  } else {
    const int k = (bid - 128) * 256 + tid;        // 2048 codes
    counts[k] = 0;
    const float* p = cb + (size_t)k * Dd;
    float r[8];
    #pragma unroll
    for (int j = 0; j < 8; ++j) r[j] = __fmul_rn(p[j], p[j]);
    for (int i = 1; i < 16; ++i) {
      #pragma unroll
      for (int j = 0; j < 8; ++j) {
        const float v = p[8 * i + j];
        r[j] = __fadd_rn(r[j], __fmul_rn(v, v));
      }
    }
    e2f[k] = __fadd_rn(__fadd_rn(__fadd_rn(r[0], r[1]), __fadd_rn(r[2], r[3])),
                       __fadd_rn(__fadd_rn(r[4], r[5]), __fadd_rn(r[6], r[7])));
  }
}

// Per-iteration register pin: the asm claims to MODIFY afr each trip, so the
// LDS copy in zh is stale from the allocator's viewpoint -> remat via
// ds_read inside the loop is illegal -> afr must stay register-resident.
// (Round 6/7/8 pathology: VGPR=80, afr re-read from LDS every iter; the DS
// pipe is per-CU shared by 4 SIMDs -> 16 b128/iter/wave x ~10 waves/CU
// saturated it at ~2.6x the MFMA floor.)
#define PIN_AFR(a)                                                            \
  asm volatile("" : "+v"((a)[0]), "+v"((a)[1]), "+v"((a)[2]), "+v"((a)[3]),   \
                    "+v"((a)[4]), "+v"((a)[5]), "+v"((a)[6]), "+v"((a)[7]),   \
                    "+v"((a)[8]), "+v"((a)[9]), "+v"((a)[10]), "+v"((a)[11]), \
                    "+v"((a)[12]), "+v"((a)[13]), "+v"((a)[14]), "+v"((a)[15]))

// Phase 1: two-sweep hi-plane bf16 MFMA scoring. 64 rows/block (1024 blocks),
// 4 waves; each wave owns all 64 rows and a 16-col slice of each chunk.
// A fragments in VGPRs (in-loop pin, see PIN_AFR); B = coalesced 1KB dwordx4
// from SOA cbh with unroll-2 named double-buffer. Main loops: zero LDS.
// Sweep A: per-lane min -> shfl over 16 cols -> LDS reduce over 4 waves ->
// exact row-global min m. Sweep B: bitwise-identical recompute, append codes
// with s < m + marg_row (marg_row = 8.7e-5*sqrt(Arow)+1e-4). Cap 16;
// candcnt>16 or 0 -> exact fallback (expected: none).
__global__ __launch_bounds__(256, 3)
void score_kernel(const float* __restrict__ z, const ushort* __restrict__ cbh,
                  const float* __restrict__ e2f, float* __restrict__ Arow,
                  ushort* __restrict__ cand_g, int* __restrict__ candcnt) {
  __shared__ __attribute__((aligned(16))) ushort zh[8192]; // 16KB z hi plane (64x128)
  __shared__ float margL[64];
  __shared__ float sredA[256];       // [row][wv]
  __shared__ float thrF[64];
  __shared__ int cntL[64];
  __shared__ ushort candL[64 * 16];  // 2KB

  const int tid = threadIdx.x;
  const int n0 = blockIdx.x * 64;                // 1024 blocks
  const int b = n0 >> 10, t0 = n0 & 1023;
  const float* zb = z + (size_t)b * DT + t0;
  const int lane = tid & 63, wv = tid >> 6;
  const int col = lane & 15, quad = lane >> 4;

  // ---- prologue: stage z hi plane (64 rows x 128 d, 16B-granule swizzled) ----
  {
    const int i = tid & 63;           // row in block
    const int half = tid >> 6;        // 0..3
    #pragma unroll
    for (int g4 = 0; g4 < 4; ++g4) {
      const int gran = half * 4 + g4;
      short8 w;
      #pragma unroll
      for (int j = 0; j < 8; ++j) {
        const int d = gran * 8 + j;
        const float v = zb[d * Tt + i];            // coalesced over i
        const unsigned u = __float_as_uint(v);
        const unsigned hb = (u + 0x7FFFu + ((u >> 16) & 1u)) & 0xFFFF0000u;
        w[j] = (short)(hb >> 16);
      }
      *(short8*)&zh[i * 128 + ((gran ^ (i & 15)) << 3)] = w;
    }
  }
  // ---- Arow: np-pairwise fp32 ||x||^2 (bitwise = reference pass; z L1-hot) ----
  if (tid < 64) {
    const float* p = zb + tid;                    // x_d = p[d*Tt]
    float r[8];
    #pragma unroll
    for (int j = 0; j < 8; ++j) {
      const float v = p[j * Tt];
      r[j] = __fmul_rn(v, v);
    }
    for (int i = 1; i < 16; ++i) {
      #pragma unroll
      for (int j = 0; j < 8; ++j) {
        const float v = p[(8 * i + j) * Tt];
        r[j] = __fadd_rn(r[j], __fmul_rn(v, v));
      }
    }
    const float A = __fadd_rn(__fadd_rn(__fadd_rn(r[0], r[1]), __fadd_rn(r[2], r[3])),
                              __fadd_rn(__fadd_rn(r[4], r[5]), __fadd_rn(r[6], r[7])));
    Arow[n0 + tid] = A;
    margL[tid] = 8.7e-5f * sqrtf(A) + 1.0e-4f;
    cntL[tid] = 0;
  }
  __syncthreads();

  // ---- A fragments: plain b128 reads into a flat static-indexed array ----
  short8 afr[16];
  #pragma unroll
  for (int rt = 0; rt < 4; ++rt)
    #pragma unroll
    for (int ks = 0; ks < 4; ++ks) {
      const int rw = rt * 16 + col;               // rw&15 == col
      afr[rt * 4 + ks] = *(const short8*)&zh[rw * 128 + (((ks * 4 + quad) ^ col) << 3)];
    }

  // per-lane B base in SOA layout: wave slice + lane*16B; frag ks at +1024B;
  // chunk stride 16384B (=8192 ushorts)
  const ushort* const bp0 = cbh + wv * 2048 + lane * 8;   // ushort units
  const float* const ep0 = e2f + wv * 16 + col;

  const float4v vzero = {0.f, 0.f, 0.f, 0.f};
  float rmin[16];
  #pragma unroll
  for (int sl = 0; sl < 16; ++sl) rmin[sl] = 1e30f;

  // ---- Sweep A: exact row-global min (barrier-free, unroll-2 dbuf) ----
  {
    short8 bA[4], bB[4];
    float eA, eB;
    #pragma unroll
    for (int ks = 0; ks < 4; ++ks) bA[ks] = *(const short8*)(bp0 + ks * 512);
    eA = ep0[0];
    for (int it = 0; it < 32; it += 2) {
      PIN_AFR(afr);                               // forbids LDS remat this iter
      const ushort* p1 = bp0 + (size_t)(it + 1) * 8192;   // prefetch it+1 -> B
      #pragma unroll
      for (int ks = 0; ks < 4; ++ks) bB[ks] = *(const short8*)(p1 + ks * 512);
      eB = ep0[(it + 1) * 64];
      {
        float4v acc[4];
        #pragma unroll
        for (int rt = 0; rt < 4; ++rt) acc[rt] = vzero;
        #pragma unroll
        for (int ks = 0; ks < 4; ++ks)
          #pragma unroll
          for (int rt = 0; rt < 4; ++rt)
            acc[rt] = __builtin_amdgcn_mfma_f32_16x16x32_bf16(afr[rt * 4 + ks], bA[ks], acc[rt], 0, 0, 0);
        #pragma unroll
        for (int rt = 0; rt < 4; ++rt)
          #pragma unroll
          for (int r = 0; r < 4; ++r) {
            const float s = fmaf(-2.0f, acc[rt][r], eA);
            rmin[rt * 4 + r] = fminf(rmin[rt * 4 + r], s);
          }
      }
      const int c2 = (it + 2 < 32) ? (it + 2) : 31;       // prefetch it+2 -> A
      const ushort* p2 = bp0 + (size_t)c2 * 8192;
      #pragma unroll
      for (int ks = 0; ks < 4; ++ks) bA[ks] = *(const short8*)(p2 + ks * 512);
      eA = ep0[c2 * 64];
      {
        float4v acc[4];
        #pragma unroll
        for (int rt = 0; rt < 4; ++rt) acc[rt] = vzero;
        #pragma unroll
        for (int ks = 0; ks < 4; ++ks)
          #pragma unroll
          for (int rt = 0; rt < 4; ++rt)
            acc[rt] = __builtin_amdgcn_mfma_f32_16x16x32_bf16(afr[rt * 4 + ks], bB[ks], acc[rt], 0, 0, 0);
        #pragma unroll
        for (int rt = 0; rt < 4; ++rt)
          #pragma unroll
          for (int r = 0; r < 4; ++r) {
            const float s = fmaf(-2.0f, acc[rt][r], eB);
            rmin[rt * 4 + r] = fminf(rmin[rt * 4 + r], s);
          }
      }
    }
  }

  // ---- exact row-global min reduce: 16 cols (shfl) x 4 waves (LDS) ----
  #pragma unroll
  for (int sl = 0; sl < 16; ++sl) {
    float v = rmin[sl];
    v = fminf(v, __shfl_xor(v, 1, 64));
    v = fminf(v, __shfl_xor(v, 2, 64));
    v = fminf(v, __shfl_xor(v, 4, 64));
    v = fminf(v, __shfl_xor(v, 8, 64));
    rmin[sl] = v;
  }
  if (col == 0) {
    #pragma unroll
    for (int sl = 0; sl < 16; ++sl) {
      const int rw = (sl >> 2) * 16 + quad * 4 + (sl & 3);
      sredA[rw * 4 + wv] = rmin[sl];
    }
  }
  __syncthreads();
  if (tid < 64) {
    const float m = fminf(fminf(sredA[tid * 4], sredA[tid * 4 + 1]),
                          fminf(sredA[tid * 4 + 2], sredA[tid * 4 + 3]));
    thrF[tid] = m + margL[tid];
  }
  __syncthreads();
  #pragma unroll
  for (int sl = 0; sl < 16; ++sl)       // reuse rmin regs as per-slot thresholds
    rmin[sl] = thrF[(sl >> 2) * 16 + quad * 4 + (sl & 3)];

  // ---- Sweep B: bitwise-identical recompute, exact-threshold append ----
  {
    short8 bA[4], bB[4];
    float eA, eB;
    #pragma unroll
    for (int ks = 0; ks < 4; ++ks) bA[ks] = *(const short8*)(bp0 + ks * 512);
    eA = ep0[0];
    for (int it = 0; it < 32; it += 2) {
      PIN_AFR(afr);                               // forbids LDS remat this iter
      const ushort* p1 = bp0 + (size_t)(it + 1) * 8192;
      #pragma unroll
      for (int ks = 0; ks < 4; ++ks) bB[ks] = *(const short8*)(p1 + ks * 512);
      eB = ep0[(it + 1) * 64];
      {
        float4v acc[4];
        #pragma unroll
        for (int rt = 0; rt < 4; ++rt) acc[rt] = vzero;
        #pragma unroll
        for (int ks = 0; ks < 4; ++ks)
          #pragma unroll
          for (int rt = 0; rt < 4; ++rt)
            acc[rt] = __builtin_amdgcn_mfma_f32_16x16x32_bf16(afr[rt * 4 + ks], bA[ks], acc[rt], 0, 0, 0);
        const int cbase = it * 64 + wv * 16 + col;
        #pragma unroll
        for (int rt = 0; rt < 4; ++rt)
          #pragma unroll
          for (int r = 0; r < 4; ++r) {
            const float s = fmaf(-2.0f, acc[rt][r], eA);
            if (s < rmin[rt * 4 + r]) {
              const int rw = rt * 16 + quad * 4 + r;
              const int pos = atomicAdd(&cntL[rw], 1);
              if (pos < 16) candL[rw * 16 + pos] = (ushort)cbase;
            }
          }
      }
      const int c2 = (it + 2 < 32) ? (it + 2) : 31;
      const ushort* p2 = bp0 + (size_t)c2 * 8192;
      #pragma unroll
      for (int ks = 0; ks < 4; ++ks) bA[ks] = *(const short8*)(p2 + ks * 512);
      eA = ep0[c2 * 64];
      {
        float4v acc[4];
        #pragma unroll
        for (int rt = 0; rt < 4; ++rt) acc[rt] = vzero;
        #pragma unroll
        for (int ks = 0; ks < 4; ++ks)
          #pragma unroll
          for (int rt = 0; rt < 4; ++rt)
            acc[rt] = __builtin_amdgcn_mfma_f32_16x16x32_bf16(afr[rt * 4 + ks], bB[ks], acc[rt], 0, 0, 0);
        const int cbase = (it + 1) * 64 + wv * 16 + col;
        #pragma unroll
        for (int rt = 0; rt < 4; ++rt)
          #pragma unroll
          for (int r = 0; r < 4; ++r) {
            const float s = fmaf(-2.0f, acc[rt][r], eB);
            if (s < rmin[rt * 4 + r]) {
              const int rw = rt * 16 + quad * 4 + r;
              const int pos = atomicAdd(&cntL[rw], 1);
              if (pos < 16) candL[rw * 16 + pos] = (ushort)cbase;
            }
          }
      }
    }
  }
  __syncthreads();
  if (tid < 64) {
    const int n = n0 + tid;
    candcnt[n] = cntL[tid];
    uint4* dst = (uint4*)(cand_g + (size_t)n * 16);
    const uint4* src = (const uint4*)(candL + tid * 16);
    dst[0] = src[0];
    dst[1] = src[1];
  }
}

// Phase 2: exact np-replica rescore + f64 commitment-loss partial via
// loss_row = A - 2*dot_win + e2[win] (f64; dot already computed for winner).
__global__ __launch_bounds__(256)
void rescore_kernel(const float* __restrict__ z, const float* __restrict__ cb,
                    const float* __restrict__ e2f, const float* __restrict__ Arow,
                    const ushort* __restrict__ cand_g, const int* __restrict__ candcnt,
                    int* __restrict__ idxbuf, int* __restrict__ counts,
                    float* __restrict__ out_idx, double* __restrict__ part) {
  const int tid = threadIdx.x;
  const int n = blockIdx.x * 256 + tid;           // 256 blocks
  const int c = candcnt[n];
  double sq = 0.0;
  if (c >= 1 && c <= 16) {                        // fallback handles the rest
    const int b = n >> 10, t = n & 1023;
    const float* zb = z + (size_t)b * DT + t;
    const float A = Arow[n];
    float best = 1e30f;
    int bk = Kk;
    double bacc = 0.0;
    for (int j = 0; j < c; ++j) {
      const int k = cand_g[(size_t)n * 16 + j];
      const float* e = cb + (size_t)k * Dd;
      double acc = 0.0;
      #pragma unroll 8
      for (int d = 0; d < 128; d += 4) {
        const float4 ev = *(const float4*)(e + d);
        acc += (double)zb[(d + 0) * Tt] * (double)ev.x;
        acc += (double)zb[(d + 1) * Tt] * (double)ev.y;
        acc += (double)zb[(d + 2) * Tt] * (double)ev.z;
        acc += (double)zb[(d + 3) * Tt] * (double)ev.w;
      }
      const float m32 = (float)acc;
      const float X = __fsub_rn(A, __fmul_rn(2.0f, m32));
      const float Dq = __fadd_rn(X, e2f[k]);
      if (Dq < best || (Dq == best && k < bk)) { best = Dq; bk = k; bacc = acc; }
    }
    idxbuf[n] = bk;
    out_idx[n] = (float)bk;
    atomicAdd(&counts[bk], 1);
    sq = (double)A - 2.0 * bacc + (double)e2f[bk];
  }
  #pragma unroll
  for (int o = 32; o > 0; o >>= 1) sq += __shfl_down(sq, o, 64);
  __shared__ double w4[4];
  if ((tid & 63) == 0) w4[tid >> 6] = sq;
  __syncthreads();
  if (tid == 0) part[blockIdx.x] = w4[0] + w4[1] + w4[2] + w4[3];
}

// Fallback: full exact scan for rows with empty/overflowed lists (expected:
// none). Contributes those rows' loss into part[256..511].
__global__ __launch_bounds__(256)
void fallback_kernel(const float* __restrict__ z, const float* __restrict__ cb,
                     const float* __restrict__ e2f, const float* __restrict__ Arow,
                     const int* __restrict__ candcnt, int* __restrict__ idxbuf,
                     int* __restrict__ counts, float* __restrict__ out_idx,
                     double* __restrict__ part) {
  __shared__ int flags[256];
  __shared__ int nf;
  __shared__ float xrow[128];
  __shared__ float rs[256];
  __shared__ int rk[256];
  const int tid = threadIdx.x;
  const int nb = blockIdx.x * 256;                // 256 blocks
  if (tid == 0) { nf = 0; part[256 + blockIdx.x] = 0.0; }
  __syncthreads();
  const int c = candcnt[nb + tid];
  const int bad = (c < 1 || c > 16) ? 1 : 0;
  flags[tid] = bad;
  if (bad) atomicAdd(&nf, 1);
  __syncthreads();
  if (nf == 0) return;                            // fast path
  double bsum = 0.0;
  for (int rr = 0; rr < 256; ++rr) {
    if (!flags[rr]) continue;                     // block-uniform
    const int n = nb + rr;
    const int b = n >> 10, t = n & 1023;
    if (tid < 128) xrow[tid] = z[(size_t)b * DT + (size_t)tid * Tt + t];
    __syncthreads();
    const float A = Arow[n];
    float best = 1e30f;
    int bk = Kk;
    for (int kk = tid * 8; kk < tid * 8 + 8; ++kk) {
      const float* e = cb + (size_t)kk * Dd;
      double acc = 0.0;
      for (int d = 0; d < 128; d += 4) {
        const float4 ev = *(const float4*)(e + d);
        acc += (double)xrow[d + 0] * (double)ev.x;
        acc += (double)xrow[d + 1] * (double)ev.y;
        acc += (double)xrow[d + 2] * (double)ev.z;
        acc += (double)xrow[d + 3] * (double)ev.w;
      }
      const float m32 = (float)acc;
      const float Dq = __fadd_rn(__fsub_rn(A, __fmul_rn(2.0f, m32)), e2f[kk]);
      if (Dq < best || (Dq == best && kk < bk)) { best = Dq; bk = kk; }
    }
    rs[tid] = best;
    rk[tid] = bk;
    __syncthreads();
    for (int o = 128; o > 0; o >>= 1) {
      if (tid < o) {
        if (rs[tid + o] < rs[tid] || (rs[tid + o] == rs[tid] && rk[tid + o] < rk[tid])) {
          rs[tid] = rs[tid + o];
          rk[tid] = rk[tid + o];
        }
      }
      __syncthreads();
    }
    if (tid == 0) {
      const int w = rk[0];
      idxbuf[n] = w;
      out_idx[n] = (float)w;
      atomicAdd(&counts[w], 1);
      const float* ew = cb + (size_t)w * Dd;
      for (int d = 0; d < 128; ++d) {
        const double dif = (double)xrow[d] - (double)ew[d];
        bsum += dif * dif;
      }
    }
    __syncthreads();
  }
  if (tid == 0) part[256 + blockIdx.x] = bsum;
}

// Gather z_q into (B,D,T) layout, LDS-transpose version: stage 64 code-rows
// (16B-granule gathers, 4x fewer L1 transactions than per-element) into
// padded LDS, then write coalesced 256B runs per d-row.
__global__ __launch_bounds__(256)
void gather_kernel(const float* __restrict__ cb, const int* __restrict__ idxbuf,
                   float* __restrict__ out0) {
  __shared__ float ef[64 * 132];     // 33.8KB, stride 132 floats (16B-aligned)
  __shared__ int sidx[64];
  const int tid = threadIdx.x;
  const int n0 = blockIdx.x * 64;    // 1024 blocks; 64 consecutive t, same b
  const int b = n0 >> 10, t0 = n0 & 1023;
  if (tid < 64) sidx[tid] = idxbuf[n0 + tid];
  __syncthreads();
  {
    const int r = tid & 63, q = tid >> 6;         // wave q stages chunk q
    const float* src = cb + (size_t)sidx[r] * Dd + q * 32;
    float* dst = ef + r * 132 + q * 32;
    #pragma unroll
    for (int j = 0; j < 8; ++j)
      *(float4*)(dst + 4 * j) = *(const float4*)(src + 4 * j);
  }
  __syncthreads();
  {
    const int l = tid & 63, w = tid >> 6;         // wave w writes d = w*32..w*32+31
    float* ob = out0 + ((size_t)b << 17) + (size_t)(w * 32) * 1024 + t0 + l;
    #pragma unroll
    for (int i = 0; i < 32; ++i)
      ob[(size_t)i * 1024] = ef[l * 132 + w * 32 + i];
  }
}

__global__ __launch_bounds__(256)
void finalize_kernel(const int* __restrict__ counts, const double* __restrict__ part,
                     float* __restrict__ out) {
  const int tid = threadIdx.x;
  __shared__ double red[256];
  double s = 0.0;
  for (int i = tid; i < 512; i += 256) s += part[i];
  red[tid] = s;
  __syncthreads();
  for (int o = 128; o > 0; o >>= 1) {
    if (tid < o) red[tid] += red[tid + o];
    __syncthreads();
  }
  const double loss = red[0];
  __syncthreads();
  double e = 0.0;
  for (int k = tid; k < 2048; k += 256) {
    const double p = (double)counts[k] / 65536.0;
    e += p * log(p + 1e-10);
  }
  red[tid] = e;
  __syncthreads();
  for (int o = 128; o > 0; o >>= 1) {
    if (tid < o) red[tid] += red[tid + o];
    __syncthreads();
  }
  if (tid == 0) {
    out[8388608] = (float)(0.25 * loss / 8388608.0);
    out[8388609] = (float)exp(-red[0]);
  }
}

extern "C" void kernel_launch(void* const* d_in, const int* in_sizes, int n_in,
                              void* d_out, int out_size, void* d_ws, size_t ws_size,
                              hipStream_t stream) {
  const float* z = (const float*)d_in[0];      // (B, D, T) fp32
  const float* cb = (const float*)d_in[1];     // (K, D) fp32
  float* out = (float*)d_out;                  // [z_q (8388608) | loss | perp | idx (65536)]
  char* ws = (char*)d_ws;
  ushort* cbh    = (ushort*)ws;
  float* e2f     = (float*)(ws + 524288);
  float* Arow    = (float*)(ws + 532480);
  int* idxbuf    = (int*)(ws + 794624);
  int* counts    = (int*)(ws + 1056768);
  double* part   = (double*)(ws + 1064960);
  ushort* cand_g = (ushort*)(ws + 1069056);
  int* candcnt   = (int*)(ws + 3166208);

  hipLaunchKernelGGL(setup_kernel,    dim3(136),  dim3(256), 0, stream, cb, cbh, e2f, counts);
  hipLaunchKernelGGL(score_kernel,    dim3(1024), dim3(256), 0, stream, z, cbh, e2f, Arow,
                     cand_g, candcnt);
  hipLaunchKernelGGL(rescore_kernel,  dim3(256),  dim3(256), 0, stream, z, cb, e2f, Arow,
                     cand_g, candcnt, idxbuf, counts, out + 8388610, part);
  hipLaunchKernelGGL(fallback_kernel, dim3(256),  dim3(256), 0, stream, z, cb, e2f, Arow,
                     candcnt, idxbuf, counts, out + 8388610, part);
  hipLaunchKernelGGL(gather_kernel,   dim3(1024), dim3(256), 0, stream, cb, idxbuf, out);
  hipLaunchKernelGGL(finalize_kernel, dim3(1),    dim3(256), 0, stream, counts, part, out);
}